// Round 4
// baseline (521.620 us; speedup 1.0000x reference)
//
#include <hip/hip_runtime.h>
#include <hip/hip_bf16.h>
#include <stdint.h>

// Harness contract: reference is pure fp32 => all d_in are float*, d_out is
// float*. We convert to bf16 internally for MFMA, accumulate fp32.

typedef __attribute__((ext_vector_type(8))) short short8;   // 8 bf16 = 4 VGPRs (MFMA A/B frag)
typedef __attribute__((ext_vector_type(4))) short short4v;  // 4 bf16 = 8B
typedef __attribute__((ext_vector_type(4))) float floatx4;  // MFMA C/D frag (16x16)
typedef __attribute__((ext_vector_type(16))) float floatx16; // MFMA C/D frag (32x32)
typedef __attribute__((ext_vector_type(4))) unsigned uint4v;

#define DEV static __device__ __forceinline__

DEV float b2f(short s) {
    unsigned u = ((unsigned)(unsigned short)s) << 16;
    return __uint_as_float(u);
}
DEV short f2b(float f) {  // round-to-nearest-even bf16
    unsigned u = __float_as_uint(f);
    u += 0x7fffu + ((u >> 16) & 1u);
    return (short)(u >> 16);
}
DEV unsigned cvtpk(float a, float b) {  // pack {bf16(a) lo, bf16(b) hi}, RNE
    unsigned r;
    asm("v_cvt_pk_bf16_f32 %0, %1, %2" : "=v"(r) : "v"(a), "v"(b));
    return r;
}

// async global->LDS, 16B per lane; HW writes lane i at wavebase + i*16
// (pass per-lane LDS ptr = base + lane*16 so source layout matches HW).
typedef const __attribute__((address_space(1))) unsigned gu32;
typedef __attribute__((address_space(3))) unsigned lu32;
DEV void g2l16(const void* g, void* l) {
    __builtin_amdgcn_global_load_lds((gu32*)(uintptr_t)g,
                                     (lu32*)(unsigned)(uintptr_t)l, 16, 0, 0);
}

// ---------------------------------------------------------------------------
// LayerNorm: y = gamma*(x-mean)/(std+eps)+beta, std = sqrt(sum((x-m)^2)/(n-1))
// fp32 in, bf16 out. one row (1024) per block of 256 threads
// ---------------------------------------------------------------------------
__global__ __launch_bounds__(256) void ln_kernel(const float* __restrict__ x,
                                                 const float* __restrict__ gamma,
                                                 const float* __restrict__ beta,
                                                 short* __restrict__ y) {
    int row = blockIdx.x;
    int t = threadIdx.x;
    float4 v = *(const float4*)(x + (size_t)row * 1024 + t * 4);
    float f[4] = {v.x, v.y, v.z, v.w};
    float s = 0.f, ss = 0.f;
#pragma unroll
    for (int i = 0; i < 4; i++) { s += f[i]; ss += f[i] * f[i]; }
#pragma unroll
    for (int off = 32; off; off >>= 1) { s += __shfl_xor(s, off); ss += __shfl_xor(ss, off); }
    __shared__ float rs[4], rss[4];
    int wid = t >> 6, lane = t & 63;
    if (lane == 0) { rs[wid] = s; rss[wid] = ss; }
    __syncthreads();
    s = rs[0] + rs[1] + rs[2] + rs[3];
    ss = rss[0] + rss[1] + rss[2] + rss[3];
    float mean = s * (1.0f / 1024.0f);
    float var = (ss - 1024.0f * mean * mean) * (1.0f / 1023.0f);
    var = fmaxf(var, 0.0f);
    float inv = 1.0f / (sqrtf(var) + 1e-5f);
    float4 g = *(const float4*)(gamma + t * 4);
    float4 bb = *(const float4*)(beta + t * 4);
    short4v o;
    o[0] = f2b(g.x * (f[0] - mean) * inv + bb.x);
    o[1] = f2b(g.y * (f[1] - mean) * inv + bb.y);
    o[2] = f2b(g.z * (f[2] - mean) * inv + bb.z);
    o[3] = f2b(g.w * (f[3] - mean) * inv + bb.w);
    *(short4v*)(y + (size_t)row * 1024 + t * 4) = o;
}

// ---------------------------------------------------------------------------
// Weight transpose + fp32->bf16: out[c*R + r] = bf16(in[r*C + c])
// ---------------------------------------------------------------------------
__global__ __launch_bounds__(256) void transpose_w(const float* __restrict__ in,
                                                   short* __restrict__ out,
                                                   int R, int C) {
    __shared__ short tile[32][33];
    int tx = threadIdx.x & 31, ty = threadIdx.x >> 5;
    int c0 = blockIdx.x * 32, r0 = blockIdx.y * 32;
#pragma unroll
    for (int i = 0; i < 4; i++)
        tile[ty + i * 8][tx] = f2b(in[(size_t)(r0 + ty + i * 8) * C + c0 + tx]);
    __syncthreads();
#pragma unroll
    for (int i = 0; i < 4; i++)
        out[(size_t)(c0 + ty + i * 8) * R + r0 + tx] = tile[tx][ty + i * 8];
}

// ---------------------------------------------------------------------------
// V^T prep: vt[bh][d][kpos] = qkv[b*2048+key][2048 + h*64 + d]  (bf16->bf16)
// Key columns PRE-PERMUTED within each 16-key group so that the attention
// PV MFMA (32x32x16, A=P) B-operand k-slot (hi*8+j) maps to key
//   perm(s) = (s&3) + 8*((s>>2)&1) + 4*(s>>3)   (involution: swaps bits 2,3)
// which is exactly the key each lane holds in its swapped-QK^T C-regs
// (crow(r,hi) = (r&3)+8*(r>>2)+4*hi). P fragments become lane-local: no
// cross-lane redistribution needed in the attn loop.
// grid: (64 key-tiles, 2 dim-tiles, 64 bh)
// ---------------------------------------------------------------------------
__global__ __launch_bounds__(256) void vtprep_kernel(const short* __restrict__ qkv,
                                                     short* __restrict__ vt) {
    __shared__ short tile[32][33];
    int tx = threadIdx.x & 31, ty = threadIdx.x >> 5;
    int bh = blockIdx.z, b = bh >> 4, h = bh & 15;
    int k0 = blockIdx.x * 32, d0 = blockIdx.y * 32;
#pragma unroll
    for (int i = 0; i < 4; i++)
        tile[ty + i * 8][tx] =
            qkv[(size_t)(b * 2048 + k0 + ty + i * 8) * 3072 + 2048 + h * 64 + d0 + tx];
    __syncthreads();
    // key (tx) -> column position (perm is its own inverse)
    int k15 = tx & 15;
    int kpos = (tx & 16) + ((k15 >> 2) & 1) * 8 + (k15 & 3) + ((k15 >> 3) & 1) * 4;
#pragma unroll
    for (int i = 0; i < 4; i++)
        vt[(size_t)bh * 131072 + (size_t)(d0 + ty + i * 8) * 2048 + k0 + kpos] =
            tile[tx][ty + i * 8];
}

// ---------------------------------------------------------------------------
// GEMM v2 (unified, counted-vmcnt pipeline):
// C[M,N] = A[M,K](bf16) * Bt[N,K]^T(bf16) (+bias) (relu) (+res)
// Tile 128x128, BK=64, 4 waves (2x2), DOUBLE-BUFFERED LDS (2x32KB = 64KB),
// depth-2 prefetch with counted s_waitcnt vmcnt(8) + raw s_barrier: loads
// stay in flight across barriers, vmcnt never drains to 0 mid-loop (the
// r3 drain structure exposed full L2/HBM latency every K-step: MfmaUtil 33%).
// Accounting (8 g2l16 per stage): prologue issues stage(0),stage(1) -> 16
// outstanding; each iter waits vmcnt(8) (own stage(kt) landed; stage(kt+1)
// still flying), barriers (all waves' stage(kt) landed), computes, lgkm-
// drains + barriers (WAR), then issues stage(kt+2) -> 16 again. Final iter
// waits vmcnt(0). 2 blocks/CU; latency hidden by 2-tile-deep prefetch.
// Grid 1D = 64*gn, XCD-chunked: xcd = id&7 owns bm in [8*xcd, 8*xcd+8),
// concurrent residency per XCD ~ 8bm x 8bn -> A 2MB + B 2MB = its 4MB L2.
// Row stride 64 elems (128B); swizzle chunk c ^= r&7 -> measured 0 conflicts.
// ---------------------------------------------------------------------------
template <int RELU, int OUTF32>
__global__ __launch_bounds__(256) void gemm_bt(const short* __restrict__ A,
                                               const short* __restrict__ Bt,
                                               const float* __restrict__ bias,
                                               const float* __restrict__ res,
                                               void* __restrict__ Cout,
                                               int M, int N, int K) {
    __shared__ short lA[2][128 * 64];
    __shared__ short lB[2][128 * 64];
    int t = threadIdx.x;
    int lin = blockIdx.x;
    int xcd = lin & 7, slot = lin >> 3;
    int bm = xcd * 8 + (slot & 7);
    int bn = slot >> 3;
    int w = t >> 6, lane = t & 63, quad = lane >> 4, l15 = lane & 15;
    int wm = (w >> 1) * 64, wn = (w & 1) * 64;
    floatx4 acc[4][4] = {};
    const int nkt = K >> 6;
    const short* Ag[4]; const short* Bg[4];
    int Sx[4];
#pragma unroll
    for (int i = 0; i < 4; i++) {
        int S = i * 256 + t;
        int r = S >> 3, c = (S & 7) ^ (r & 7);
        Ag[i] = A + (size_t)(bm * 128 + r) * K + c * 8;
        Bg[i] = Bt + (size_t)(bn * 128 + r) * K + c * 8;
        Sx[i] = S * 8;
    }
    auto stage = [&](int kt, int bufi) {
#pragma unroll
        for (int i = 0; i < 4; i++) {
            g2l16(Ag[i] + kt * 64, &lA[bufi][Sx[i]]);
            g2l16(Bg[i] + kt * 64, &lB[bufi][Sx[i]]);
        }
    };
    stage(0, 0);
    stage(1, 1);
#pragma unroll 2
    for (int kt = 0; kt < nkt; kt++) {
        int cur = kt & 1;
        if (kt + 1 < nkt)
            asm volatile("s_waitcnt vmcnt(8)" ::: "memory");  // own stage(kt) done
        else
            asm volatile("s_waitcnt vmcnt(0)" ::: "memory");  // last tile: drain
        __builtin_amdgcn_s_barrier();   // all waves' stage(kt) landed
        asm volatile("" ::: "memory");
        short8 af[2][4], bf[2][4];
#pragma unroll
        for (int kc = 0; kc < 2; kc++) {
#pragma unroll
            for (int mt = 0; mt < 4; mt++) {
                int row = wm + mt * 16 + l15;
                int c = (kc * 4 + quad) ^ (row & 7);
                af[kc][mt] = *(short8*)&lA[cur][row * 64 + c * 8];
            }
#pragma unroll
            for (int nt = 0; nt < 4; nt++) {
                int row = wn + nt * 16 + l15;
                int c = (kc * 4 + quad) ^ (row & 7);
                bf[kc][nt] = *(short8*)&lB[cur][row * 64 + c * 8];
            }
        }
#pragma unroll
        for (int kc = 0; kc < 2; kc++)
#pragma unroll
            for (int mt = 0; mt < 4; mt++)
#pragma unroll
                for (int nt = 0; nt < 4; nt++)
                    acc[mt][nt] = __builtin_amdgcn_mfma_f32_16x16x32_bf16(
                        af[kc][mt], bf[kc][nt], acc[mt][nt], 0, 0, 0);
        asm volatile("s_waitcnt lgkmcnt(0)" ::: "memory");  // reads of buf done
        __builtin_amdgcn_s_barrier();                       // WAR: safe to restage
        asm volatile("" ::: "memory");
        if (kt + 2 < nkt) stage(kt + 2, cur);   // in flight across next barriers
    }
#pragma unroll
    for (int mt = 0; mt < 4; mt++) {
#pragma unroll
        for (int nt = 0; nt < 4; nt++) {
            int col = bn * 128 + wn + nt * 16 + l15;
            float bv = bias ? bias[col] : 0.0f;
#pragma unroll
            for (int r = 0; r < 4; r++) {
                int row = bm * 128 + wm + mt * 16 + quad * 4 + r;
                float v = acc[mt][nt][r] + bv;
                if (RELU) v = fmaxf(v, 0.0f);
                if (res) v += res[(size_t)row * N + col];
                if (OUTF32)
                    ((float*)Cout)[(size_t)row * N + col] = v;
                else
                    ((short*)Cout)[(size_t)row * N + col] = f2b(v);
            }
        }
    }
}

// ---------------------------------------------------------------------------
// Flash attention v4.1: swapped-QK^T 32x32x16 MFMA, P fully in registers.
// 1D grid 1024, block 256 = 4 waves, 32 q/wave, KVBLK=64.
// __launch_bounds__(256,4): cap unified VGPR+AGPR at 128/thread so 4 blocks
// (16 waves) fit per CU -> single fully-resident pass.
// kt loop unrolled x2: cur compile-time -> LDS addrs hoisted, less VALU.
// XCD swizzle: xcd=id&7 owns 8 (b,h) pairs x 16 qtiles -> per-XCD K/V
// working set = 4MB = its L2.
// S^T = mfma(A=K, B=Q): lane holds q = lane&31, 32 of 64 keys at
// crow(r,hi) = (r&3)+8*(r>>2)+4*hi (+32 per kt block). Softmax exp2 +
// row-partial sum are lane-local. V key-columns are pre-permuted (vtprep)
// so PV's A-operand k-slot (hi*8+j) == the key in P-reg j: the P fragment
// is 4x v_cvt_pk_bf16_f32 of adjacent regs. No lP, no shuffles in loop.
// Double-buffered K/V staged with g2l16; one barrier per iter (syncthreads
// drains vmcnt(0); the prefetch issued after the PREVIOUS barrier has a
// full compute phase to land).
// Base-2 softmax: Q prescaled by 2^-5*log2(e); p = exp2(S) via v_exp_f32.
// ---------------------------------------------------------------------------
__global__ __launch_bounds__(256, 4) void attn_kernel(const short* __restrict__ qkv,
                                                      const short* __restrict__ vt,
                                                      short* __restrict__ out) {
    __shared__ short lK[2][64 * 64];
    __shared__ short lV[2][64 * 64];
    __shared__ float lsbuf[4][32];
    int t = threadIdx.x;
    int w = t >> 6, lane = t & 63, l31 = lane & 31, hi = lane >> 5;
    int lin = blockIdx.x;
    int xcd = lin & 7, slot = lin >> 3;
    int hb = xcd * 8 + (slot & 7);   // 64 (b,h) combos, 8 per XCD
    int qt = slot >> 3;              // 0..15
    int b = hb >> 4, h = hb & 15;
    int qrow0 = b * 2048 + qt * 128 + w * 32;

    // Q B-fragments (col = q = l31, k = d = ks*16 + hi*8 + j),
    // prescaled by 2^-5 * log2(e)
    short8 qb[4];
#pragma unroll
    for (int ks = 0; ks < 4; ks++) {
        short8 q = *(const short8*)(qkv + (size_t)(qrow0 + l31) * 3072 +
                                    h * 64 + ks * 16 + hi * 8);
#pragma unroll
        for (int i = 0; i < 8; i++) q[i] = f2b(b2f(q[i]) * 0.04508422f);
        qb[ks] = q;
    }

    float l_s = 0.f;
    floatx16 o0 = {}, o1 = {};   // O cols d = l31 (+32 for o1), rows q = crow

    int S0 = t, S1 = 256 + t;
    int r0 = S0 >> 3, c0 = (S0 & 7) ^ (r0 & 7);
    int r1 = S1 >> 3, c1 = (S1 & 7) ^ (r1 & 7);
    const short* Kg0 = qkv + (size_t)(b * 2048 + r0) * 3072 + 1024 + h * 64 + c0 * 8;
    const short* Kg1 = qkv + (size_t)(b * 2048 + r1) * 3072 + 1024 + h * 64 + c1 * 8;
    const short* Vg0 = vt + (size_t)hb * 131072 + (size_t)r0 * 2048 + c0 * 8;
    const short* Vg1 = vt + (size_t)hb * 131072 + (size_t)r1 * 2048 + c1 * 8;

    auto stage = [&](int kt, int bufi) {
        int key0 = kt * 64;
        g2l16(Kg0 + (size_t)key0 * 3072, &lK[bufi][S0 * 8]);
        g2l16(Kg1 + (size_t)key0 * 3072, &lK[bufi][S1 * 8]);
        g2l16(Vg0 + key0, &lV[bufi][S0 * 8]);
        g2l16(Vg1 + key0, &lV[bufi][S1 * 8]);
    };

    stage(0, 0);
#pragma unroll 2
    for (int kt = 0; kt < 32; kt++) {
        int cur = kt & 1;
        __syncthreads();               // drains vmcnt: buf[cur] ready; WAR ok
        if (kt < 31) stage(kt + 1, cur ^ 1);   // lands during compute below

        // S^T = K (Q*2^-5*log2e)^T : s0 = keys 0..31, s1 = keys 32..63
        floatx16 s0 = {}, s1 = {};
#pragma unroll
        for (int ks = 0; ks < 4; ks++) {
            int cd = ks * 2 + hi;
            int ra = l31, rb = 32 + l31;
            short8 ka = *(short8*)&lK[cur][ra * 64 + ((cd ^ (ra & 7))) * 8];
            short8 kb = *(short8*)&lK[cur][rb * 64 + ((cd ^ (rb & 7))) * 8];
            s0 = __builtin_amdgcn_mfma_f32_32x32x16_bf16(ka, qb[ks], s0, 0, 0, 0);
            s1 = __builtin_amdgcn_mfma_f32_32x32x16_bf16(kb, qb[ks], s1, 0, 0, 0);
        }

        // p = 2^S in place; lane-local partial row-sum (this lane's 32 keys)
        float ps = 0.f;
#pragma unroll
        for (int r = 0; r < 16; r++) {
            float e0 = __builtin_amdgcn_exp2f(s0[r]);
            float e1 = __builtin_amdgcn_exp2f(s1[r]);
            s0[r] = e0; s1[r] = e1;
            ps += e0 + e1;
        }
        l_s += ps;

        // O += P V ; P frag = cvt_pk of adjacent regs (keys pre-matched by
        // the vt column permutation)
#pragma unroll
        for (int ks = 0; ks < 4; ks++) {
            unsigned w0, w1, w2, w3;
            if (ks == 0) {
                w0 = cvtpk(s0[0], s0[1]);  w1 = cvtpk(s0[2], s0[3]);
                w2 = cvtpk(s0[4], s0[5]);  w3 = cvtpk(s0[6], s0[7]);
            } else if (ks == 1) {
                w0 = cvtpk(s0[8], s0[9]);  w1 = cvtpk(s0[10], s0[11]);
                w2 = cvtpk(s0[12], s0[13]); w3 = cvtpk(s0[14], s0[15]);
            } else if (ks == 2) {
                w0 = cvtpk(s1[0], s1[1]);  w1 = cvtpk(s1[2], s1[3]);
                w2 = cvtpk(s1[4], s1[5]);  w3 = cvtpk(s1[6], s1[7]);
            } else {
                w0 = cvtpk(s1[8], s1[9]);  w1 = cvtpk(s1[10], s1[11]);
                w2 = cvtpk(s1[12], s1[13]); w3 = cvtpk(s1[14], s1[15]);
            }
            short8 pa = __builtin_bit_cast(short8, (uint4v){w0, w1, w2, w3});
            int cd = ks * 2 + hi;
            int ra = l31, rb = 32 + l31;
            short8 va = *(short8*)&lV[cur][ra * 64 + ((cd ^ (ra & 7))) * 8];
            short8 vb = *(short8*)&lV[cur][rb * 64 + ((cd ^ (rb & 7))) * 8];
            o0 = __builtin_amdgcn_mfma_f32_32x32x16_bf16(pa, va, o0, 0, 0, 0);
            o1 = __builtin_amdgcn_mfma_f32_32x32x16_bf16(pa, vb, o1, 0, 0, 0);
        }
    }

    // full row-sum: this lane's half + partner half (lane ^ 32, same q)
    float tot = l_s + __shfl_xor(l_s, 32);
    if (lane < 32) lsbuf[w][l31] = 1.0f / tot;
    __syncthreads();   // order ds_write before cross-lane ds_read

#pragma unroll
    for (int r = 0; r < 16; r++) {
        int qd = (r & 3) + 8 * (r >> 2) + 4 * hi;
        float rls = lsbuf[w][qd];
        size_t rowoff = (size_t)(qrow0 + qd) * 1024 + h * 64 + l31;
        out[rowoff] = f2b(o0[r] * rls);
        out[rowoff + 32] = f2b(o1[r] * rls);
    }
}

// ---------------------------------------------------------------------------
extern "C" void kernel_launch(void* const* d_in, const int* in_sizes, int n_in,
                              void* d_out, int out_size, void* d_ws, size_t ws_size,
                              hipStream_t stream) {
    const float* x      = (const float*)d_in[0];
    const float* w_qkv  = (const float*)d_in[1];
    const float* w_out  = (const float*)d_in[2];
    const float* b_out  = (const float*)d_in[3];
    const float* w1     = (const float*)d_in[4];
    const float* b1     = (const float*)d_in[5];
    const float* w2     = (const float*)d_in[6];
    const float* b2     = (const float*)d_in[7];
    const float* gamma1 = (const float*)d_in[8];
    const float* beta1  = (const float*)d_in[9];
    const float* gamma2 = (const float*)d_in[10];
    const float* beta2  = (const float*)d_in[11];
    float* out = (float*)d_out;

    // Workspace layout (byte offsets, 136MB high-water):
    //   0: wqkvT 6MB | 6: woutT 2MB | 8: w1T 8MB | 16: w2T 8MB
    //  24: h1 16MB (LN1 out -> attn out -> LN2 out)
    //  40: qkv 48MB + 88: vt 16MB  (both dead after attn; ff1 64MB spans both)
    // 104: x2 fp32 32MB (live to end)
    char* ws = (char*)d_ws;
    const size_t MB = 1024u * 1024u;
    short* wqkvT = (short*)(ws + 0 * MB);
    short* woutT = (short*)(ws + 6 * MB);
    short* w1T   = (short*)(ws + 8 * MB);
    short* w2T   = (short*)(ws + 16 * MB);
    short* h1    = (short*)(ws + 24 * MB);
    short* qkv   = (short*)(ws + 40 * MB);
    short* vt    = (short*)(ws + 88 * MB);
    short* ff1   = (short*)(ws + 40 * MB);
    float* x2    = (float*)(ws + 104 * MB);
    short* attn  = h1;   // h1 dead after QKV gemm
    short* h2    = h1;   // attn out dead after Wout gemm

    dim3 blk(256);
    transpose_w<<<dim3(96, 32), blk, 0, stream>>>(w_qkv, wqkvT, 1024, 3072);
    transpose_w<<<dim3(32, 32), blk, 0, stream>>>(w_out, woutT, 1024, 1024);
    transpose_w<<<dim3(128, 32), blk, 0, stream>>>(w1, w1T, 1024, 4096);
    transpose_w<<<dim3(32, 128), blk, 0, stream>>>(w2, w2T, 4096, 1024);

    ln_kernel<<<8192, blk, 0, stream>>>(x, gamma1, beta1, h1);
    // grids are 1D: 64 bm-tiles x gn bn-tiles, XCD-chunked inside the kernel
    gemm_bt<0, 0><<<dim3(64 * 24), blk, 0, stream>>>(h1, wqkvT, nullptr, nullptr,
                                                     qkv, 8192, 3072, 1024);
    vtprep_kernel<<<dim3(64, 2, 64), blk, 0, stream>>>(qkv, vt);
    attn_kernel<<<dim3(1024), blk, 0, stream>>>(qkv, vt, attn);
    gemm_bt<0, 1><<<dim3(64 * 8), blk, 0, stream>>>(attn, woutT, b_out, x, x2,
                                                    8192, 1024, 1024);
    ln_kernel<<<8192, blk, 0, stream>>>(x2, gamma2, beta2, h2);
    gemm_bt<1, 0><<<dim3(64 * 32), blk, 0, stream>>>(h2, w1T, b1, nullptr, ff1,
                                                     8192, 4096, 1024);
    gemm_bt<0, 1><<<dim3(64 * 8), blk, 0, stream>>>(ff1, w2T, b2, x2, out,
                                                    8192, 1024, 4096);
}

// Round 5
// 497.345 us; speedup vs baseline: 1.0488x; 1.0488x over previous
//
#include <hip/hip_runtime.h>
#include <hip/hip_bf16.h>
#include <stdint.h>

// Harness contract: reference is pure fp32 => all d_in are float*, d_out is
// float*. We convert to bf16 internally for MFMA, accumulate fp32.

typedef __attribute__((ext_vector_type(8))) short short8;   // 8 bf16 = 4 VGPRs (MFMA A/B frag)
typedef __attribute__((ext_vector_type(4))) short short4v;  // 4 bf16 = 8B
typedef __attribute__((ext_vector_type(4))) float floatx4;  // MFMA C/D frag (16x16)
typedef __attribute__((ext_vector_type(16))) float floatx16; // MFMA C/D frag (32x32)
typedef __attribute__((ext_vector_type(4))) unsigned uint4v;

#define DEV static __device__ __forceinline__

DEV float b2f(short s) {
    unsigned u = ((unsigned)(unsigned short)s) << 16;
    return __uint_as_float(u);
}
DEV short f2b(float f) {  // round-to-nearest-even bf16
    unsigned u = __float_as_uint(f);
    u += 0x7fffu + ((u >> 16) & 1u);
    return (short)(u >> 16);
}
DEV unsigned cvtpk(float a, float b) {  // pack {bf16(a) lo, bf16(b) hi}, RNE
    unsigned r;
    asm("v_cvt_pk_bf16_f32 %0, %1, %2" : "=v"(r) : "v"(a), "v"(b));
    return r;
}

// async global->LDS, 16B per lane; HW writes lane i at wavebase + i*16
// (pass per-lane LDS ptr = base + lane*16 so source layout matches HW).
typedef const __attribute__((address_space(1))) unsigned gu32;
typedef __attribute__((address_space(3))) unsigned lu32;
DEV void g2l16(const void* g, void* l) {
    __builtin_amdgcn_global_load_lds((gu32*)(uintptr_t)g,
                                     (lu32*)(unsigned)(uintptr_t)l, 16, 0, 0);
}

#define BARRIER() do { asm volatile("" ::: "memory"); \
    __builtin_amdgcn_s_barrier(); \
    asm volatile("" ::: "memory"); } while (0)

// ---------------------------------------------------------------------------
// LayerNorm: y = gamma*(x-mean)/(std+eps)+beta, std = sqrt(sum((x-m)^2)/(n-1))
// fp32 in, bf16 out. one row (1024) per block of 256 threads
// ---------------------------------------------------------------------------
__global__ __launch_bounds__(256) void ln_kernel(const float* __restrict__ x,
                                                 const float* __restrict__ gamma,
                                                 const float* __restrict__ beta,
                                                 short* __restrict__ y) {
    int row = blockIdx.x;
    int t = threadIdx.x;
    float4 v = *(const float4*)(x + (size_t)row * 1024 + t * 4);
    float f[4] = {v.x, v.y, v.z, v.w};
    float s = 0.f, ss = 0.f;
#pragma unroll
    for (int i = 0; i < 4; i++) { s += f[i]; ss += f[i] * f[i]; }
#pragma unroll
    for (int off = 32; off; off >>= 1) { s += __shfl_xor(s, off); ss += __shfl_xor(ss, off); }
    __shared__ float rs[4], rss[4];
    int wid = t >> 6, lane = t & 63;
    if (lane == 0) { rs[wid] = s; rss[wid] = ss; }
    __syncthreads();
    s = rs[0] + rs[1] + rs[2] + rs[3];
    ss = rss[0] + rss[1] + rss[2] + rss[3];
    float mean = s * (1.0f / 1024.0f);
    float var = (ss - 1024.0f * mean * mean) * (1.0f / 1023.0f);
    var = fmaxf(var, 0.0f);
    float inv = 1.0f / (sqrtf(var) + 1e-5f);
    float4 g = *(const float4*)(gamma + t * 4);
    float4 bb = *(const float4*)(beta + t * 4);
    short4v o;
    o[0] = f2b(g.x * (f[0] - mean) * inv + bb.x);
    o[1] = f2b(g.y * (f[1] - mean) * inv + bb.y);
    o[2] = f2b(g.z * (f[2] - mean) * inv + bb.z);
    o[3] = f2b(g.w * (f[3] - mean) * inv + bb.w);
    *(short4v*)(y + (size_t)row * 1024 + t * 4) = o;
}

// ---------------------------------------------------------------------------
// Weight transpose + fp32->bf16: out[c*R + r] = bf16(in[r*C + c])
// ---------------------------------------------------------------------------
__global__ __launch_bounds__(256) void transpose_w(const float* __restrict__ in,
                                                   short* __restrict__ out,
                                                   int R, int C) {
    __shared__ short tile[32][33];
    int tx = threadIdx.x & 31, ty = threadIdx.x >> 5;
    int c0 = blockIdx.x * 32, r0 = blockIdx.y * 32;
#pragma unroll
    for (int i = 0; i < 4; i++)
        tile[ty + i * 8][tx] = f2b(in[(size_t)(r0 + ty + i * 8) * C + c0 + tx]);
    __syncthreads();
#pragma unroll
    for (int i = 0; i < 4; i++)
        out[(size_t)(c0 + ty + i * 8) * R + r0 + tx] = tile[tx][ty + i * 8];
}

// ---------------------------------------------------------------------------
// V^T prep: vt[bh][d][kpos] = qkv[b*2048+key][2048 + h*64 + d]  (bf16->bf16)
// Key columns PRE-PERMUTED within each 16-key group so that the attention
// PV MFMA (32x32x16, A=P) B-operand k-slot (hi*8+j) maps to key
//   perm(s) = (s&3) + 8*((s>>2)&1) + 4*(s>>3)   (involution: swaps bits 2,3)
// which is exactly the key each lane holds in its swapped-QK^T C-regs
// (crow(r,hi) = (r&3)+8*(r>>2)+4*hi). P fragments become lane-local.
// grid: (64 key-tiles, 2 dim-tiles, 64 bh)
// ---------------------------------------------------------------------------
__global__ __launch_bounds__(256) void vtprep_kernel(const short* __restrict__ qkv,
                                                     short* __restrict__ vt) {
    __shared__ short tile[32][33];
    int tx = threadIdx.x & 31, ty = threadIdx.x >> 5;
    int bh = blockIdx.z, b = bh >> 4, h = bh & 15;
    int k0 = blockIdx.x * 32, d0 = blockIdx.y * 32;
#pragma unroll
    for (int i = 0; i < 4; i++)
        tile[ty + i * 8][tx] =
            qkv[(size_t)(b * 2048 + k0 + ty + i * 8) * 3072 + 2048 + h * 64 + d0 + tx];
    __syncthreads();
    // key (tx) -> column position (perm is its own inverse)
    int k15 = tx & 15;
    int kpos = (tx & 16) + ((k15 >> 2) & 1) * 8 + (k15 & 3) + ((k15 >> 3) & 1) * 4;
#pragma unroll
    for (int i = 0; i < 4; i++)
        vt[(size_t)bh * 131072 + (size_t)(d0 + ty + i * 8) * 2048 + k0 + kpos] =
            tile[tx][ty + i * 8];
}

// ---------------------------------------------------------------------------
// GEMM (BK=64, r3-proven): C = A * Bt^T (+bias)(relu)(+res). Tile 128x128,
// 4 waves, 32KB LDS -> 3 blocks/CU. Used for QKV. 0 bank conflicts.
// ---------------------------------------------------------------------------
template <int RELU, int OUTF32>
__global__ __launch_bounds__(256) void gemm_bt_k64(const short* __restrict__ A,
                                                   const short* __restrict__ Bt,
                                                   const float* __restrict__ bias,
                                                   const float* __restrict__ res,
                                                   void* __restrict__ Cout,
                                                   int M, int N, int K) {
    __shared__ short lA[128 * 64];
    __shared__ short lB[128 * 64];
    int t = threadIdx.x;
    int bn = blockIdx.x, bm = blockIdx.y;
    int w = t >> 6, lane = t & 63, quad = lane >> 4, l15 = lane & 15;
    int wm = (w >> 1) * 64, wn = (w & 1) * 64;
    floatx4 acc[4][4] = {};
    const int nkt = K >> 6;
    const short* Ag[4]; const short* Bg[4];
    short* lAp[4]; short* lBp[4];
#pragma unroll
    for (int i = 0; i < 4; i++) {
        int S = i * 256 + t;
        int r = S >> 3, c = (S & 7) ^ (r & 7);
        Ag[i] = A + (size_t)(bm * 128 + r) * K + c * 8;
        Bg[i] = Bt + (size_t)(bn * 128 + r) * K + c * 8;
        lAp[i] = &lA[S * 8];
        lBp[i] = &lB[S * 8];
    }
    for (int kt = 0; kt < nkt; kt++) {
#pragma unroll
        for (int i = 0; i < 4; i++) {
            g2l16(Ag[i] + kt * 64, lAp[i]);
            g2l16(Bg[i] + kt * 64, lBp[i]);
        }
        __syncthreads();   // drains vmcnt(0)
        short8 af[2][4], bf[2][4];
#pragma unroll
        for (int kc = 0; kc < 2; kc++) {
#pragma unroll
            for (int mt = 0; mt < 4; mt++) {
                int row = wm + mt * 16 + l15;
                int c = (kc * 4 + quad) ^ (row & 7);
                af[kc][mt] = *(short8*)&lA[row * 64 + c * 8];
            }
#pragma unroll
            for (int nt = 0; nt < 4; nt++) {
                int row = wn + nt * 16 + l15;
                int c = (kc * 4 + quad) ^ (row & 7);
                bf[kc][nt] = *(short8*)&lB[row * 64 + c * 8];
            }
        }
#pragma unroll
        for (int kc = 0; kc < 2; kc++)
#pragma unroll
            for (int mt = 0; mt < 4; mt++)
#pragma unroll
                for (int nt = 0; nt < 4; nt++)
                    acc[mt][nt] = __builtin_amdgcn_mfma_f32_16x16x32_bf16(
                        af[kc][mt], bf[kc][nt], acc[mt][nt], 0, 0, 0);
        __syncthreads();
    }
#pragma unroll
    for (int mt = 0; mt < 4; mt++) {
#pragma unroll
        for (int nt = 0; nt < 4; nt++) {
            int col = bn * 128 + wn + nt * 16 + l15;
            float bv = bias ? bias[col] : 0.0f;
#pragma unroll
            for (int r = 0; r < 4; r++) {
                int row = bm * 128 + wm + mt * 16 + quad * 4 + r;
                float v = acc[mt][nt][r] + bv;
                if (RELU) v = fmaxf(v, 0.0f);
                if (res) v += res[(size_t)row * N + col];
                if (OUTF32)
                    ((float*)Cout)[(size_t)row * N + col] = v;
                else
                    ((short*)Cout)[(size_t)row * N + col] = f2b(v);
            }
        }
    }
}

// ---------------------------------------------------------------------------
// GEMM (BK=128 + XCD swizzle, r3-proven): for the grid-limited N=1024 GEMMs
// (Wout, FF2: 512 blocks = 2/CU). LDS 64KB. Each XCD's 64 co-resident blocks
// form an 8x8 (bm,bn) sub-grid -> tiles shared through that XCD's L2.
// ---------------------------------------------------------------------------
template <int RELU, int OUTF32>
__global__ __launch_bounds__(256) void gemm_bt_k128(const short* __restrict__ A,
                                                    const short* __restrict__ Bt,
                                                    const float* __restrict__ bias,
                                                    const float* __restrict__ res,
                                                    void* __restrict__ Cout,
                                                    int M, int N, int K) {
    __shared__ short lA[128 * 128];
    __shared__ short lB[128 * 128];
    int t = threadIdx.x;
    int lin = blockIdx.x;
    int xcd = lin & 7, slot = lin >> 3;
    int bm = xcd * 8 + (slot & 7);   // this XCD owns bm in [8*xcd, 8*xcd+8)
    int bn = slot >> 3;              // 0..7
    int w = t >> 6, lane = t & 63, quad = lane >> 4, l15 = lane & 15;
    int wm = (w >> 1) * 64, wn = (w & 1) * 64;
    floatx4 acc[4][4] = {};
    const int nkt = K >> 7;
    const short* Ag[8]; const short* Bg[8];
    short* lAp[8]; short* lBp[8];
#pragma unroll
    for (int i = 0; i < 8; i++) {
        int S = i * 256 + t;
        int r = S >> 4, c = (S & 15) ^ (r & 15);
        Ag[i] = A + (size_t)(bm * 128 + r) * K + c * 8;
        Bg[i] = Bt + (size_t)(bn * 128 + r) * K + c * 8;
        lAp[i] = &lA[S * 8];
        lBp[i] = &lB[S * 8];
    }
    for (int kt = 0; kt < nkt; kt++) {
#pragma unroll
        for (int i = 0; i < 8; i++) {
            g2l16(Ag[i] + kt * 128, lAp[i]);
            g2l16(Bg[i] + kt * 128, lBp[i]);
        }
        __syncthreads();   // drains vmcnt(0)
#pragma unroll
        for (int kc = 0; kc < 4; kc++) {
            short8 af[4], bf[4];
#pragma unroll
            for (int mt = 0; mt < 4; mt++) {
                int row = wm + mt * 16 + l15;
                int c = (kc * 4 + quad) ^ (row & 15);
                af[mt] = *(short8*)&lA[row * 128 + c * 8];
            }
#pragma unroll
            for (int nt = 0; nt < 4; nt++) {
                int row = wn + nt * 16 + l15;
                int c = (kc * 4 + quad) ^ (row & 15);
                bf[nt] = *(short8*)&lB[row * 128 + c * 8];
            }
#pragma unroll
            for (int mt = 0; mt < 4; mt++)
#pragma unroll
                for (int nt = 0; nt < 4; nt++)
                    acc[mt][nt] = __builtin_amdgcn_mfma_f32_16x16x32_bf16(
                        af[mt], bf[nt], acc[mt][nt], 0, 0, 0);
        }
        __syncthreads();
    }
#pragma unroll
    for (int mt = 0; mt < 4; mt++) {
#pragma unroll
        for (int nt = 0; nt < 4; nt++) {
            int col = bn * 128 + wn + nt * 16 + l15;
            float bv = bias ? bias[col] : 0.0f;
#pragma unroll
            for (int r = 0; r < 4; r++) {
                int row = bm * 128 + wm + mt * 16 + quad * 4 + r;
                float v = acc[mt][nt][r] + bv;
                if (RELU) v = fmaxf(v, 0.0f);
                if (res) v += res[(size_t)row * N + col];
                if (OUTF32)
                    ((float*)Cout)[(size_t)row * N + col] = v;
                else
                    ((short*)Cout)[(size_t)row * N + col] = f2b(v);
            }
        }
    }
}

// ---------------------------------------------------------------------------
// GEMM 256x256 8-phase (m201-template port). BK=64, 512 threads = 8 waves
// (2M x 4N), per-wave 128x64 out (acc[8][4]), LDS 128KB (2dbuf x (A 256x64 +
// B 256x64)), 1 block/CU. Per ktile m (buf = m&1), 4 phases x {ds-read / 2
// g2l16 / barrier / 16 MFMA in setprio(1) / barrier}:
//   p0: read kc0 (af0[8]+bf0[4]); stage B01 of m+1 (other buf); MFMA mt0-3 kc0
//   p1: read kc1 (af1+bf1);       stage B23 of m+1;             MFMA mt4-7 kc0
//       + lgkmcnt(0) before closing barrier: ALL reads of buf complete ->
//       buf restage-safe from p2 (in-flight ds_read vs g2l16 WAR race fix)
//   p2:                           stage A01 of m+2 (this buf);  MFMA mt0-3 kc1
//   p3:                           stage A23 of m+2;             MFMA mt4-7 kc1
//       + s_waitcnt vmcnt(4) before closing barrier (serves ktile m+1 entry).
// FIFO accounting (2 loads/phase/thread): ktile j's pieces issue at
// (j-2).p2/p3 [A] and (j-1).p0/p1 [B]; at end of m.p3 outstanding =
// (m+1)'s 8 + (m+2)'s A 4 = 12 -> vmcnt(4) retires exactly (m+1)'s 8.
// vmcnt NEVER 0 mid-loop (T3+T4); setprio = T5; XOR swizzle = T2 (0 confl).
// Grid 1D, XCD-chunked: xcd=lin&7 -> bm = xcd*4 + (s&3), bn = s>>2 (M=8192).
// ---------------------------------------------------------------------------
template <int RELU, int OUTF32>
__global__ __launch_bounds__(512, 2) void gemm256(const short* __restrict__ A,
                                                  const short* __restrict__ Bt,
                                                  const float* __restrict__ bias,
                                                  const float* __restrict__ res,
                                                  void* __restrict__ Cout,
                                                  int M, int N, int K) {
    __shared__ short lA[2][256 * 64];
    __shared__ short lB[2][256 * 64];
    int t = threadIdx.x;
    int lin = blockIdx.x;
    int xcd = lin & 7, s = lin >> 3;
    int bm = xcd * 4 + (s & 3);   // M=8192 -> 32 m-tiles, 4 per XCD chunk
    int bn = s >> 2;
    int w = t >> 6, lane = t & 63, quad = lane >> 4, l15 = lane & 15;
    int wm = (w >> 2) * 128, wn = (w & 3) * 64;
    floatx4 acc[8][4] = {};
    const int nkt = K >> 6;
    const short* Ag[4]; const short* Bg[4];
    int Sx[4];
#pragma unroll
    for (int i = 0; i < 4; i++) {
        int S = i * 512 + t;
        int r = S >> 3, c = (S & 7) ^ (r & 7);
        Ag[i] = A + (size_t)(bm * 256 + r) * K + c * 8;
        Bg[i] = Bt + (size_t)(bn * 256 + r) * K + c * 8;
        Sx[i] = S * 8;
    }
    // piece j of ktile kt: j<4 -> A round j; j>=4 -> B round j-4
    auto piece = [&](int kt, int j) {
        int buf = kt & 1;
        if (j < 4) g2l16(Ag[j] + kt * 64, &lA[buf][Sx[j]]);
        else       g2l16(Bg[j - 4] + kt * 64, &lB[buf][Sx[j - 4]]);
    };
    // prologue: ktile0 all 8 pieces, ktile1 A-part (matches steady-state FIFO)
#pragma unroll
    for (int j = 0; j < 8; j++) piece(0, j);
    if (nkt > 1) { piece(1, 0); piece(1, 1); piece(1, 2); piece(1, 3); }
    if (nkt > 1) asm volatile("s_waitcnt vmcnt(4)" ::: "memory");
    else         asm volatile("s_waitcnt vmcnt(0)" ::: "memory");
    BARRIER();

#pragma unroll 2
    for (int m = 0; m < nkt; m++) {
        int buf = m & 1;
        short8 af0[8], bf0[4], af1[8], bf1[4];
        // ---- p0: read kc0; stage B01(m+1); MFMA mt0-3 kc0
#pragma unroll
        for (int mt = 0; mt < 8; mt++) {
            int row = wm + mt * 16 + l15;
            af0[mt] = *(short8*)&lA[buf][row * 64 + (quad ^ (row & 7)) * 8];
        }
#pragma unroll
        for (int nt = 0; nt < 4; nt++) {
            int row = wn + nt * 16 + l15;
            bf0[nt] = *(short8*)&lB[buf][row * 64 + (quad ^ (row & 7)) * 8];
        }
        if (m + 1 < nkt) { piece(m + 1, 4); piece(m + 1, 5); }
        BARRIER();
        __builtin_amdgcn_s_setprio(1);
#pragma unroll
        for (int mt = 0; mt < 4; mt++)
#pragma unroll
            for (int nt = 0; nt < 4; nt++)
                acc[mt][nt] = __builtin_amdgcn_mfma_f32_16x16x32_bf16(
                    af0[mt], bf0[nt], acc[mt][nt], 0, 0, 0);
        __builtin_amdgcn_s_setprio(0);
        BARRIER();
        // ---- p1: read kc1; stage B23(m+1); MFMA mt4-7 kc0
#pragma unroll
        for (int mt = 0; mt < 8; mt++) {
            int row = wm + mt * 16 + l15;
            af1[mt] = *(short8*)&lA[buf][row * 64 + ((4 + quad) ^ (row & 7)) * 8];
        }
#pragma unroll
        for (int nt = 0; nt < 4; nt++) {
            int row = wn + nt * 16 + l15;
            bf1[nt] = *(short8*)&lB[buf][row * 64 + ((4 + quad) ^ (row & 7)) * 8];
        }
        if (m + 1 < nkt) { piece(m + 1, 6); piece(m + 1, 7); }
        BARRIER();
        __builtin_amdgcn_s_setprio(1);
#pragma unroll
        for (int mt = 4; mt < 8; mt++)
#pragma unroll
            for (int nt = 0; nt < 4; nt++)
                acc[mt][nt] = __builtin_amdgcn_mfma_f32_16x16x32_bf16(
                    af0[mt], bf0[nt], acc[mt][nt], 0, 0, 0);
        __builtin_amdgcn_s_setprio(0);
        asm volatile("s_waitcnt lgkmcnt(0)" ::: "memory");  // all buf reads done
        BARRIER();
        // ---- p2: stage A01(m+2) into buf (read-free now); MFMA mt0-3 kc1
        if (m + 2 < nkt) { piece(m + 2, 0); piece(m + 2, 1); }
        BARRIER();
        __builtin_amdgcn_s_setprio(1);
#pragma unroll
        for (int mt = 0; mt < 4; mt++)
#pragma unroll
            for (int nt = 0; nt < 4; nt++)
                acc[mt][nt] = __builtin_amdgcn_mfma_f32_16x16x32_bf16(
                    af1[mt], bf1[nt], acc[mt][nt], 0, 0, 0);
        __builtin_amdgcn_s_setprio(0);
        BARRIER();
        // ---- p3: stage A23(m+2); MFMA mt4-7 kc1; counted wait for m+1
        if (m + 2 < nkt) { piece(m + 2, 2); piece(m + 2, 3); }
        BARRIER();
        __builtin_amdgcn_s_setprio(1);
#pragma unroll
        for (int mt = 4; mt < 8; mt++)
#pragma unroll
            for (int nt = 0; nt < 4; nt++)
                acc[mt][nt] = __builtin_amdgcn_mfma_f32_16x16x32_bf16(
                    af1[mt], bf1[nt], acc[mt][nt], 0, 0, 0);
        __builtin_amdgcn_s_setprio(0);
        if (m + 1 < nkt) {
            if (m + 2 < nkt) asm volatile("s_waitcnt vmcnt(4)" ::: "memory");
            else             asm volatile("s_waitcnt vmcnt(0)" ::: "memory");
        }
        BARRIER();
    }
#pragma unroll
    for (int mt = 0; mt < 8; mt++) {
#pragma unroll
        for (int nt = 0; nt < 4; nt++) {
            int col = bn * 256 + wn + nt * 16 + l15;
            float bv = bias ? bias[col] : 0.0f;
#pragma unroll
            for (int r = 0; r < 4; r++) {
                int row = bm * 256 + wm + mt * 16 + quad * 4 + r;
                float v = acc[mt][nt][r] + bv;
                if (RELU) v = fmaxf(v, 0.0f);
                if (res) v += res[(size_t)row * N + col];
                if (OUTF32)
                    ((float*)Cout)[(size_t)row * N + col] = v;
                else
                    ((short*)Cout)[(size_t)row * N + col] = f2b(v);
            }
        }
    }
}

// ---------------------------------------------------------------------------
// Flash attention v4.1: swapped-QK^T 32x32x16 MFMA, P fully in registers.
// 1D grid 1024, block 256 = 4 waves, 32 q/wave, KVBLK=64. See r3 notes.
// ---------------------------------------------------------------------------
__global__ __launch_bounds__(256, 4) void attn_kernel(const short* __restrict__ qkv,
                                                      const short* __restrict__ vt,
                                                      short* __restrict__ out) {
    __shared__ short lK[2][64 * 64];
    __shared__ short lV[2][64 * 64];
    __shared__ float lsbuf[4][32];
    int t = threadIdx.x;
    int w = t >> 6, lane = t & 63, l31 = lane & 31, hi = lane >> 5;
    int lin = blockIdx.x;
    int xcd = lin & 7, slot = lin >> 3;
    int hb = xcd * 8 + (slot & 7);   // 64 (b,h) combos, 8 per XCD
    int qt = slot >> 3;              // 0..15
    int b = hb >> 4, h = hb & 15;
    int qrow0 = b * 2048 + qt * 128 + w * 32;

    // Q B-fragments (col = q = l31, k = d = ks*16 + hi*8 + j),
    // prescaled by 2^-5 * log2(e)
    short8 qb[4];
#pragma unroll
    for (int ks = 0; ks < 4; ks++) {
        short8 q = *(const short8*)(qkv + (size_t)(qrow0 + l31) * 3072 +
                                    h * 64 + ks * 16 + hi * 8);
#pragma unroll
        for (int i = 0; i < 8; i++) q[i] = f2b(b2f(q[i]) * 0.04508422f);
        qb[ks] = q;
    }

    float l_s = 0.f;
    floatx16 o0 = {}, o1 = {};   // O cols d = l31 (+32 for o1), rows q = crow

    int S0 = t, S1 = 256 + t;
    int r0 = S0 >> 3, c0 = (S0 & 7) ^ (r0 & 7);
    int r1 = S1 >> 3, c1 = (S1 & 7) ^ (r1 & 7);
    const short* Kg0 = qkv + (size_t)(b * 2048 + r0) * 3072 + 1024 + h * 64 + c0 * 8;
    const short* Kg1 = qkv + (size_t)(b * 2048 + r1) * 3072 + 1024 + h * 64 + c1 * 8;
    const short* Vg0 = vt + (size_t)hb * 131072 + (size_t)r0 * 2048 + c0 * 8;
    const short* Vg1 = vt + (size_t)hb * 131072 + (size_t)r1 * 2048 + c1 * 8;

    auto stage = [&](int kt, int bufi) {
        int key0 = kt * 64;
        g2l16(Kg0 + (size_t)key0 * 3072, &lK[bufi][S0 * 8]);
        g2l16(Kg1 + (size_t)key0 * 3072, &lK[bufi][S1 * 8]);
        g2l16(Vg0 + key0, &lV[bufi][S0 * 8]);
        g2l16(Vg1 + key0, &lV[bufi][S1 * 8]);
    };

    stage(0, 0);
#pragma unroll 2
    for (int kt = 0; kt < 32; kt++) {
        int cur = kt & 1;
        __syncthreads();               // drains vmcnt: buf[cur] ready; WAR ok
        if (kt < 31) stage(kt + 1, cur ^ 1);   // lands during compute below

        // S^T = K (Q*2^-5*log2e)^T : s0 = keys 0..31, s1 = keys 32..63
        floatx16 s0 = {}, s1 = {};
#pragma unroll
        for (int ks = 0; ks < 4; ks++) {
            int cd = ks * 2 + hi;
            int ra = l31, rb = 32 + l31;
            short8 ka = *(short8*)&lK[cur][ra * 64 + ((cd ^ (ra & 7))) * 8];
            short8 kb = *(short8*)&lK[cur][rb * 64 + ((cd ^ (rb & 7))) * 8];
            s0 = __builtin_amdgcn_mfma_f32_32x32x16_bf16(ka, qb[ks], s0, 0, 0, 0);
            s1 = __builtin_amdgcn_mfma_f32_32x32x16_bf16(kb, qb[ks], s1, 0, 0, 0);
        }

        // p = 2^S in place; lane-local partial row-sum (this lane's 32 keys)
        float ps = 0.f;
#pragma unroll
        for (int r = 0; r < 16; r++) {
            float e0 = __builtin_amdgcn_exp2f(s0[r]);
            float e1 = __builtin_amdgcn_exp2f(s1[r]);
            s0[r] = e0; s1[r] = e1;
            ps += e0 + e1;
        }
        l_s += ps;

        // O += P V ; P frag = cvt_pk of adjacent regs (keys pre-matched by
        // the vt column permutation)
#pragma unroll
        for (int ks = 0; ks < 4; ks++) {
            unsigned w0, w1, w2, w3;
            if (ks == 0) {
                w0 = cvtpk(s0[0], s0[1]);  w1 = cvtpk(s0[2], s0[3]);
                w2 = cvtpk(s0[4], s0[5]);  w3 = cvtpk(s0[6], s0[7]);
            } else if (ks == 1) {
                w0 = cvtpk(s0[8], s0[9]);  w1 = cvtpk(s0[10], s0[11]);
                w2 = cvtpk(s0[12], s0[13]); w3 = cvtpk(s0[14], s0[15]);
            } else if (ks == 2) {
                w0 = cvtpk(s1[0], s1[1]);  w1 = cvtpk(s1[2], s1[3]);
                w2 = cvtpk(s1[4], s1[5]);  w3 = cvtpk(s1[6], s1[7]);
            } else {
                w0 = cvtpk(s1[8], s1[9]);  w1 = cvtpk(s1[10], s1[11]);
                w2 = cvtpk(s1[12], s1[13]); w3 = cvtpk(s1[14], s1[15]);
            }
            short8 pa = __builtin_bit_cast(short8, (uint4v){w0, w1, w2, w3});
            int cd = ks * 2 + hi;
            int ra = l31, rb = 32 + l31;
            short8 va = *(short8*)&lV[cur][ra * 64 + ((cd ^ (ra & 7))) * 8];
            short8 vb = *(short8*)&lV[cur][rb * 64 + ((cd ^ (rb & 7))) * 8];
            o0 = __builtin_amdgcn_mfma_f32_32x32x16_bf16(pa, va, o0, 0, 0, 0);
            o1 = __builtin_amdgcn_mfma_f32_32x32x16_bf16(pa, vb, o1, 0, 0, 0);
        }
    }

    // full row-sum: this lane's half + partner half (lane ^ 32, same q)
    float tot = l_s + __shfl_xor(l_s, 32);
    if (lane < 32) lsbuf[w][l31] = 1.0f / tot;
    __syncthreads();   // order ds_write before cross-lane ds_read

#pragma unroll
    for (int r = 0; r < 16; r++) {
        int qd = (r & 3) + 8 * (r >> 2) + 4 * hi;
        float rls = lsbuf[w][qd];
        size_t rowoff = (size_t)(qrow0 + qd) * 1024 + h * 64 + l31;
        out[rowoff] = f2b(o0[r] * rls);
        out[rowoff + 32] = f2b(o1[r] * rls);
    }
}

// ---------------------------------------------------------------------------
extern "C" void kernel_launch(void* const* d_in, const int* in_sizes, int n_in,
                              void* d_out, int out_size, void* d_ws, size_t ws_size,
                              hipStream_t stream) {
    const float* x      = (const float*)d_in[0];
    const float* w_qkv  = (const float*)d_in[1];
    const float* w_out  = (const float*)d_in[2];
    const float* b_out  = (const float*)d_in[3];
    const float* w1     = (const float*)d_in[4];
    const float* b1     = (const float*)d_in[5];
    const float* w2     = (const float*)d_in[6];
    const float* b2     = (const float*)d_in[7];
    const float* gamma1 = (const float*)d_in[8];
    const float* beta1  = (const float*)d_in[9];
    const float* gamma2 = (const float*)d_in[10];
    const float* beta2  = (const float*)d_in[11];
    float* out = (float*)d_out;

    // Workspace layout (byte offsets, 136MB high-water):
    //   0: wqkvT 6MB | 6: woutT 2MB | 8: w1T 8MB | 16: w2T 8MB
    //  24: h1 16MB (LN1 out -> attn out -> LN2 out)
    //  40: qkv 48MB + 88: vt 16MB  (both dead after attn; ff1 64MB spans both)
    // 104: x2 fp32 32MB (live to end)
    char* ws = (char*)d_ws;
    const size_t MB = 1024u * 1024u;
    short* wqkvT = (short*)(ws + 0 * MB);
    short* woutT = (short*)(ws + 6 * MB);
    short* w1T   = (short*)(ws + 8 * MB);
    short* w2T   = (short*)(ws + 16 * MB);
    short* h1    = (short*)(ws + 24 * MB);
    short* qkv   = (short*)(ws + 40 * MB);
    short* vt    = (short*)(ws + 88 * MB);
    short* ff1   = (short*)(ws + 40 * MB);
    float* x2    = (float*)(ws + 104 * MB);
    short* attn  = h1;   // h1 dead after QKV gemm
    short* h2    = h1;   // attn out dead after Wout gemm

    dim3 blk(256);
    transpose_w<<<dim3(96, 32), blk, 0, stream>>>(w_qkv, wqkvT, 1024, 3072);
    transpose_w<<<dim3(32, 32), blk, 0, stream>>>(w_out, woutT, 1024, 1024);
    transpose_w<<<dim3(128, 32), blk, 0, stream>>>(w1, w1T, 1024, 4096);
    transpose_w<<<dim3(32, 128), blk, 0, stream>>>(w2, w2T, 4096, 1024);

    ln_kernel<<<8192, blk, 0, stream>>>(x, gamma1, beta1, h1);
    gemm_bt_k64<0, 0><<<dim3(24, 64), blk, 0, stream>>>(h1, wqkvT, nullptr, nullptr,
                                                        qkv, 8192, 3072, 1024);
    vtprep_kernel<<<dim3(64, 2, 64), blk, 0, stream>>>(qkv, vt);
    attn_kernel<<<dim3(1024), blk, 0, stream>>>(qkv, vt, attn);
    gemm_bt_k128<0, 1><<<dim3(512), blk, 0, stream>>>(attn, woutT, b_out, x, x2,
                                                      8192, 1024, 1024);
    ln_kernel<<<8192, blk, 0, stream>>>(x2, gamma2, beta2, h2);
    // FF1 on the 256^2 8-phase kernel: 32x16 = 512 blocks = 2 clean rounds
    gemm256<1, 0><<<dim3(512), dim3(512), 0, stream>>>(h2, w1T, b1, nullptr, ff1,
                                                       8192, 4096, 1024);
    gemm_bt_k128<0, 1><<<dim3(512), blk, 0, stream>>>(ff1, w2T, b2, x2, out,
                                                      8192, 1024, 4096);
}

// Round 6
// 490.068 us; speedup vs baseline: 1.0644x; 1.0148x over previous
//
#include <hip/hip_runtime.h>
#include <hip/hip_bf16.h>
#include <stdint.h>

// Harness contract: reference is pure fp32 => all d_in are float*, d_out is
// float*. We convert to bf16 internally for MFMA, accumulate fp32.

typedef __attribute__((ext_vector_type(8))) short short8;   // 8 bf16 = 4 VGPRs (MFMA A/B frag)
typedef __attribute__((ext_vector_type(4))) short short4v;  // 4 bf16 = 8B
typedef __attribute__((ext_vector_type(4))) float floatx4;  // MFMA C/D frag (16x16)
typedef __attribute__((ext_vector_type(16))) float floatx16; // MFMA C/D frag (32x32)
typedef __attribute__((ext_vector_type(4))) unsigned uint4v;

#define DEV static __device__ __forceinline__

DEV float b2f(short s) {
    unsigned u = ((unsigned)(unsigned short)s) << 16;
    return __uint_as_float(u);
}
DEV short f2b(float f) {  // round-to-nearest-even bf16
    unsigned u = __float_as_uint(f);
    u += 0x7fffu + ((u >> 16) & 1u);
    return (short)(u >> 16);
}
DEV unsigned cvtpk(float a, float b) {  // pack {bf16(a) lo, bf16(b) hi}, RNE
    unsigned r;
    asm("v_cvt_pk_bf16_f32 %0, %1, %2" : "=v"(r) : "v"(a), "v"(b));
    return r;
}

// async global->LDS, 16B per lane; HW writes lane i at wavebase + i*16
// (pass per-lane LDS ptr = base + lane*16 so source layout matches HW).
typedef const __attribute__((address_space(1))) unsigned gu32;
typedef __attribute__((address_space(3))) unsigned lu32;
DEV void g2l16(const void* g, void* l) {
    __builtin_amdgcn_global_load_lds((gu32*)(uintptr_t)g,
                                     (lu32*)(unsigned)(uintptr_t)l, 16, 0, 0);
}

#define BARRIER() do { asm volatile("" ::: "memory"); \
    __builtin_amdgcn_s_barrier(); \
    asm volatile("" ::: "memory"); } while (0)

// ---------------------------------------------------------------------------
// LayerNorm: y = gamma*(x-mean)/(std+eps)+beta, std = sqrt(sum((x-m)^2)/(n-1))
// fp32 in, bf16 out. one row (1024) per block of 256 threads
// ---------------------------------------------------------------------------
__global__ __launch_bounds__(256) void ln_kernel(const float* __restrict__ x,
                                                 const float* __restrict__ gamma,
                                                 const float* __restrict__ beta,
                                                 short* __restrict__ y) {
    int row = blockIdx.x;
    int t = threadIdx.x;
    float4 v = *(const float4*)(x + (size_t)row * 1024 + t * 4);
    float f[4] = {v.x, v.y, v.z, v.w};
    float s = 0.f, ss = 0.f;
#pragma unroll
    for (int i = 0; i < 4; i++) { s += f[i]; ss += f[i] * f[i]; }
#pragma unroll
    for (int off = 32; off; off >>= 1) { s += __shfl_xor(s, off); ss += __shfl_xor(ss, off); }
    __shared__ float rs[4], rss[4];
    int wid = t >> 6, lane = t & 63;
    if (lane == 0) { rs[wid] = s; rss[wid] = ss; }
    __syncthreads();
    s = rs[0] + rs[1] + rs[2] + rs[3];
    ss = rss[0] + rss[1] + rss[2] + rss[3];
    float mean = s * (1.0f / 1024.0f);
    float var = (ss - 1024.0f * mean * mean) * (1.0f / 1023.0f);
    var = fmaxf(var, 0.0f);
    float inv = 1.0f / (sqrtf(var) + 1e-5f);
    float4 g = *(const float4*)(gamma + t * 4);
    float4 bb = *(const float4*)(beta + t * 4);
    short4v o;
    o[0] = f2b(g.x * (f[0] - mean) * inv + bb.x);
    o[1] = f2b(g.y * (f[1] - mean) * inv + bb.y);
    o[2] = f2b(g.z * (f[2] - mean) * inv + bb.z);
    o[3] = f2b(g.w * (f[3] - mean) * inv + bb.w);
    *(short4v*)(y + (size_t)row * 1024 + t * 4) = o;
}

// ---------------------------------------------------------------------------
// Weight transpose + fp32->bf16: out[c*R + r] = bf16(in[r*C + c])
// ---------------------------------------------------------------------------
__global__ __launch_bounds__(256) void transpose_w(const float* __restrict__ in,
                                                   short* __restrict__ out,
                                                   int R, int C) {
    __shared__ short tile[32][33];
    int tx = threadIdx.x & 31, ty = threadIdx.x >> 5;
    int c0 = blockIdx.x * 32, r0 = blockIdx.y * 32;
#pragma unroll
    for (int i = 0; i < 4; i++)
        tile[ty + i * 8][tx] = f2b(in[(size_t)(r0 + ty + i * 8) * C + c0 + tx]);
    __syncthreads();
#pragma unroll
    for (int i = 0; i < 4; i++)
        out[(size_t)(c0 + ty + i * 8) * R + r0 + tx] = tile[tx][ty + i * 8];
}

// ---------------------------------------------------------------------------
// V^T prep: vt[bh][d][kpos] = qkv[b*2048+key][2048 + h*64 + d]  (bf16->bf16)
// Key columns PRE-PERMUTED within each 16-key group so that the attention
// PV MFMA (32x32x16, A=P) B-operand k-slot (hi*8+j) maps to key
//   perm(s) = (s&3) + 8*((s>>2)&1) + 4*(s>>3)   (involution: swaps bits 2,3)
// which is exactly the key each lane holds in its swapped-QK^T C-regs
// (crow(r,hi) = (r&3)+8*(r>>2)+4*hi). P fragments become lane-local.
// grid: (64 key-tiles, 2 dim-tiles, 64 bh)
// ---------------------------------------------------------------------------
__global__ __launch_bounds__(256) void vtprep_kernel(const short* __restrict__ qkv,
                                                     short* __restrict__ vt) {
    __shared__ short tile[32][33];
    int tx = threadIdx.x & 31, ty = threadIdx.x >> 5;
    int bh = blockIdx.z, b = bh >> 4, h = bh & 15;
    int k0 = blockIdx.x * 32, d0 = blockIdx.y * 32;
#pragma unroll
    for (int i = 0; i < 4; i++)
        tile[ty + i * 8][tx] =
            qkv[(size_t)(b * 2048 + k0 + ty + i * 8) * 3072 + 2048 + h * 64 + d0 + tx];
    __syncthreads();
    // key (tx) -> column position (perm is its own inverse)
    int k15 = tx & 15;
    int kpos = (tx & 16) + ((k15 >> 2) & 1) * 8 + (k15 & 3) + ((k15 >> 3) & 1) * 4;
#pragma unroll
    for (int i = 0; i < 4; i++)
        vt[(size_t)bh * 131072 + (size_t)(d0 + ty + i * 8) * 2048 + k0 + kpos] =
            tile[tx][ty + i * 8];
}

// ---------------------------------------------------------------------------
// GEMM (BK=64, r3-proven): C = A * Bt^T (+bias)(relu)(+res). Tile 128x128,
// 4 waves, 32KB LDS -> 3 blocks/CU. Used for QKV. 0 bank conflicts.
// ---------------------------------------------------------------------------
template <int RELU, int OUTF32>
__global__ __launch_bounds__(256) void gemm_bt_k64(const short* __restrict__ A,
                                                   const short* __restrict__ Bt,
                                                   const float* __restrict__ bias,
                                                   const float* __restrict__ res,
                                                   void* __restrict__ Cout,
                                                   int M, int N, int K) {
    __shared__ short lA[128 * 64];
    __shared__ short lB[128 * 64];
    int t = threadIdx.x;
    int bn = blockIdx.x, bm = blockIdx.y;
    int w = t >> 6, lane = t & 63, quad = lane >> 4, l15 = lane & 15;
    int wm = (w >> 1) * 64, wn = (w & 1) * 64;
    floatx4 acc[4][4] = {};
    const int nkt = K >> 6;
    const short* Ag[4]; const short* Bg[4];
    short* lAp[4]; short* lBp[4];
#pragma unroll
    for (int i = 0; i < 4; i++) {
        int S = i * 256 + t;
        int r = S >> 3, c = (S & 7) ^ (r & 7);
        Ag[i] = A + (size_t)(bm * 128 + r) * K + c * 8;
        Bg[i] = Bt + (size_t)(bn * 128 + r) * K + c * 8;
        lAp[i] = &lA[S * 8];
        lBp[i] = &lB[S * 8];
    }
    for (int kt = 0; kt < nkt; kt++) {
#pragma unroll
        for (int i = 0; i < 4; i++) {
            g2l16(Ag[i] + kt * 64, lAp[i]);
            g2l16(Bg[i] + kt * 64, lBp[i]);
        }
        __syncthreads();   // drains vmcnt(0)
        short8 af[2][4], bf[2][4];
#pragma unroll
        for (int kc = 0; kc < 2; kc++) {
#pragma unroll
            for (int mt = 0; mt < 4; mt++) {
                int row = wm + mt * 16 + l15;
                int c = (kc * 4 + quad) ^ (row & 7);
                af[kc][mt] = *(short8*)&lA[row * 64 + c * 8];
            }
#pragma unroll
            for (int nt = 0; nt < 4; nt++) {
                int row = wn + nt * 16 + l15;
                int c = (kc * 4 + quad) ^ (row & 7);
                bf[kc][nt] = *(short8*)&lB[row * 64 + c * 8];
            }
        }
#pragma unroll
        for (int kc = 0; kc < 2; kc++)
#pragma unroll
            for (int mt = 0; mt < 4; mt++)
#pragma unroll
                for (int nt = 0; nt < 4; nt++)
                    acc[mt][nt] = __builtin_amdgcn_mfma_f32_16x16x32_bf16(
                        af[kc][mt], bf[kc][nt], acc[mt][nt], 0, 0, 0);
        __syncthreads();
    }
#pragma unroll
    for (int mt = 0; mt < 4; mt++) {
#pragma unroll
        for (int nt = 0; nt < 4; nt++) {
            int col = bn * 128 + wn + nt * 16 + l15;
            float bv = bias ? bias[col] : 0.0f;
#pragma unroll
            for (int r = 0; r < 4; r++) {
                int row = bm * 128 + wm + mt * 16 + quad * 4 + r;
                float v = acc[mt][nt][r] + bv;
                if (RELU) v = fmaxf(v, 0.0f);
                if (res) v += res[(size_t)row * N + col];
                if (OUTF32)
                    ((float*)Cout)[(size_t)row * N + col] = v;
                else
                    ((short*)Cout)[(size_t)row * N + col] = f2b(v);
            }
        }
    }
}

// ---------------------------------------------------------------------------
// GEMM 256x256 8-phase (m201-template port, r5-proven on FF1). BK=64, 512
// threads = 8 waves (2M x 4N), per-wave 128x64 out (acc[8][4]), LDS 128KB,
// 1 block/CU. See r4 notes for the 4-phase/ktile schedule + FIFO accounting.
// vmcnt NEVER 0 mid-loop (T3+T4); setprio = T5; XOR swizzle = T2 (0 confl).
// Grid 1D, XCD-chunked: xcd=lin&7 -> bm = xcd*4 + (s&3), bn = s>>2 (M=8192).
// ---------------------------------------------------------------------------
template <int RELU, int OUTF32>
__global__ __launch_bounds__(512, 2) void gemm256(const short* __restrict__ A,
                                                  const short* __restrict__ Bt,
                                                  const float* __restrict__ bias,
                                                  const float* __restrict__ res,
                                                  void* __restrict__ Cout,
                                                  int M, int N, int K) {
    __shared__ short lA[2][256 * 64];
    __shared__ short lB[2][256 * 64];
    int t = threadIdx.x;
    int lin = blockIdx.x;
    int xcd = lin & 7, s = lin >> 3;
    int bm = xcd * 4 + (s & 3);   // M=8192 -> 32 m-tiles, 4 per XCD chunk
    int bn = s >> 2;
    int w = t >> 6, lane = t & 63, quad = lane >> 4, l15 = lane & 15;
    int wm = (w >> 2) * 128, wn = (w & 3) * 64;
    floatx4 acc[8][4] = {};
    const int nkt = K >> 6;
    const short* Ag[4]; const short* Bg[4];
    int Sx[4];
#pragma unroll
    for (int i = 0; i < 4; i++) {
        int S = i * 512 + t;
        int r = S >> 3, c = (S & 7) ^ (r & 7);
        Ag[i] = A + (size_t)(bm * 256 + r) * K + c * 8;
        Bg[i] = Bt + (size_t)(bn * 256 + r) * K + c * 8;
        Sx[i] = S * 8;
    }
    // piece j of ktile kt: j<4 -> A round j; j>=4 -> B round j-4
    auto piece = [&](int kt, int j) {
        int buf = kt & 1;
        if (j < 4) g2l16(Ag[j] + kt * 64, &lA[buf][Sx[j]]);
        else       g2l16(Bg[j - 4] + kt * 64, &lB[buf][Sx[j - 4]]);
    };
    // prologue: ktile0 all 8 pieces, ktile1 A-part (matches steady-state FIFO)
#pragma unroll
    for (int j = 0; j < 8; j++) piece(0, j);
    if (nkt > 1) { piece(1, 0); piece(1, 1); piece(1, 2); piece(1, 3); }
    if (nkt > 1) asm volatile("s_waitcnt vmcnt(4)" ::: "memory");
    else         asm volatile("s_waitcnt vmcnt(0)" ::: "memory");
    BARRIER();

#pragma unroll 2
    for (int m = 0; m < nkt; m++) {
        int buf = m & 1;
        short8 af0[8], bf0[4], af1[8], bf1[4];
        // ---- p0: read kc0; stage B01(m+1); MFMA mt0-3 kc0
#pragma unroll
        for (int mt = 0; mt < 8; mt++) {
            int row = wm + mt * 16 + l15;
            af0[mt] = *(short8*)&lA[buf][row * 64 + (quad ^ (row & 7)) * 8];
        }
#pragma unroll
        for (int nt = 0; nt < 4; nt++) {
            int row = wn + nt * 16 + l15;
            bf0[nt] = *(short8*)&lB[buf][row * 64 + (quad ^ (row & 7)) * 8];
        }
        if (m + 1 < nkt) { piece(m + 1, 4); piece(m + 1, 5); }
        BARRIER();
        __builtin_amdgcn_s_setprio(1);
#pragma unroll
        for (int mt = 0; mt < 4; mt++)
#pragma unroll
            for (int nt = 0; nt < 4; nt++)
                acc[mt][nt] = __builtin_amdgcn_mfma_f32_16x16x32_bf16(
                    af0[mt], bf0[nt], acc[mt][nt], 0, 0, 0);
        __builtin_amdgcn_s_setprio(0);
        BARRIER();
        // ---- p1: read kc1; stage B23(m+1); MFMA mt4-7 kc0
#pragma unroll
        for (int mt = 0; mt < 8; mt++) {
            int row = wm + mt * 16 + l15;
            af1[mt] = *(short8*)&lA[buf][row * 64 + ((4 + quad) ^ (row & 7)) * 8];
        }
#pragma unroll
        for (int nt = 0; nt < 4; nt++) {
            int row = wn + nt * 16 + l15;
            bf1[nt] = *(short8*)&lB[buf][row * 64 + ((4 + quad) ^ (row & 7)) * 8];
        }
        if (m + 1 < nkt) { piece(m + 1, 6); piece(m + 1, 7); }
        BARRIER();
        __builtin_amdgcn_s_setprio(1);
#pragma unroll
        for (int mt = 4; mt < 8; mt++)
#pragma unroll
            for (int nt = 0; nt < 4; nt++)
                acc[mt][nt] = __builtin_amdgcn_mfma_f32_16x16x32_bf16(
                    af0[mt], bf0[nt], acc[mt][nt], 0, 0, 0);
        __builtin_amdgcn_s_setprio(0);
        asm volatile("s_waitcnt lgkmcnt(0)" ::: "memory");  // all buf reads done
        BARRIER();
        // ---- p2: stage A01(m+2) into buf (read-free now); MFMA mt0-3 kc1
        if (m + 2 < nkt) { piece(m + 2, 0); piece(m + 2, 1); }
        BARRIER();
        __builtin_amdgcn_s_setprio(1);
#pragma unroll
        for (int mt = 0; mt < 4; mt++)
#pragma unroll
            for (int nt = 0; nt < 4; nt++)
                acc[mt][nt] = __builtin_amdgcn_mfma_f32_16x16x32_bf16(
                    af1[mt], bf1[nt], acc[mt][nt], 0, 0, 0);
        __builtin_amdgcn_s_setprio(0);
        BARRIER();
        // ---- p3: stage A23(m+2); MFMA mt4-7 kc1; counted wait for m+1
        if (m + 2 < nkt) { piece(m + 2, 2); piece(m + 2, 3); }
        BARRIER();
        __builtin_amdgcn_s_setprio(1);
#pragma unroll
        for (int mt = 4; mt < 8; mt++)
#pragma unroll
            for (int nt = 0; nt < 4; nt++)
                acc[mt][nt] = __builtin_amdgcn_mfma_f32_16x16x32_bf16(
                    af1[mt], bf1[nt], acc[mt][nt], 0, 0, 0);
        __builtin_amdgcn_s_setprio(0);
        if (m + 1 < nkt) {
            if (m + 2 < nkt) asm volatile("s_waitcnt vmcnt(4)" ::: "memory");
            else             asm volatile("s_waitcnt vmcnt(0)" ::: "memory");
        }
        BARRIER();
    }
#pragma unroll
    for (int mt = 0; mt < 8; mt++) {
#pragma unroll
        for (int nt = 0; nt < 4; nt++) {
            int col = bn * 256 + wn + nt * 16 + l15;
            float bv = bias ? bias[col] : 0.0f;
#pragma unroll
            for (int r = 0; r < 4; r++) {
                int row = bm * 256 + wm + mt * 16 + quad * 4 + r;
                float v = acc[mt][nt][r] + bv;
                if (RELU) v = fmaxf(v, 0.0f);
                if (res) v += res[(size_t)row * N + col];
                if (OUTF32)
                    ((float*)Cout)[(size_t)row * N + col] = v;
                else
                    ((short*)Cout)[(size_t)row * N + col] = f2b(v);
            }
        }
    }
}

// ---------------------------------------------------------------------------
// GEMM 256x128 pipelined (for the N=1024 GEMMs: Wout, FF2). BK=64, 512
// threads = 8 waves (4M x 2N), per-wave 64x64 out (acc[4][4]), LDS 96KB
// (2dbuf x (A 256x64 32KB + B 128x64 16KB)) -> 1 block/CU. Grid 32x8 = 256
// blocks = exactly 1/CU, XCD-chunked (xcd owns bm[4x,4x+4) x all 8 bn ->
// per-ktile slab A 128KB + B 128KB hot in its L2).
// Per ktile m (buf=m&1), 2 phases x {8 ds_reads / stage / barrier / 16 MFMA
// in setprio / barrier}:
//   p0: read kc0 (af0[4]+bf0[4]); stage B(m+1) 2 pieces (other buf); MFMA kc0
//   p1: read kc1; lgkmcnt(0) [ALL reads of buf done] + BARRIER ->
//       stage A(m+2) 4 pieces into buf (read-free); MFMA kc1; counted wait.
// FIFO (6 pieces/ktile/thread): A(j) issues at (j-2).p1, B(j) at (j-1).p0.
// At end of m: outstanding = A(m+1)4 + B(m+1)2 + A(m+2)4 = 10; vmcnt(4)
// retires exactly A(m+1)+B(m+1). vmcnt NEVER 0 mid-loop (T3+T4); setprio T5;
// XOR swizzle T2. Tail: m+2>=nkt -> vmcnt(0); m+1>=nkt -> none.
// ---------------------------------------------------------------------------
template <int RELU, int OUTF32>
__global__ __launch_bounds__(512, 2) void gemm256n128(const short* __restrict__ A,
                                                      const short* __restrict__ Bt,
                                                      const float* __restrict__ bias,
                                                      const float* __restrict__ res,
                                                      void* __restrict__ Cout,
                                                      int M, int N, int K) {
    __shared__ short lA[2][256 * 64];
    __shared__ short lB[2][128 * 64];
    int t = threadIdx.x;
    int lin = blockIdx.x;
    int xcd = lin & 7, s = lin >> 3;
    int bm = xcd * 4 + (s & 3);   // M=8192 -> 32 m-tiles, 4 per XCD chunk
    int bn = s >> 2;              // 0..7 (N=1024)
    int w = t >> 6, lane = t & 63, quad = lane >> 4, l15 = lane & 15;
    int wm = (w >> 1) * 64, wn = (w & 1) * 64;
    floatx4 acc[4][4] = {};
    const int nkt = K >> 6;
    const short* Ag[4]; const short* Bg[2];
    int SxA[4], SxB[2];
#pragma unroll
    for (int i = 0; i < 4; i++) {
        int S = i * 512 + t;
        int r = S >> 3, c = (S & 7) ^ (r & 7);
        Ag[i] = A + (size_t)(bm * 256 + r) * K + c * 8;
        SxA[i] = S * 8;
    }
#pragma unroll
    for (int i = 0; i < 2; i++) {
        int S = i * 512 + t;
        int r = S >> 3, c = (S & 7) ^ (r & 7);
        Bg[i] = Bt + (size_t)(bn * 128 + r) * K + c * 8;
        SxB[i] = S * 8;
    }
    auto stageA = [&](int kt) {
        int buf = kt & 1;
#pragma unroll
        for (int i = 0; i < 4; i++) g2l16(Ag[i] + kt * 64, &lA[buf][SxA[i]]);
    };
    auto stageB = [&](int kt) {
        int buf = kt & 1;
#pragma unroll
        for (int i = 0; i < 2; i++) g2l16(Bg[i] + kt * 64, &lB[buf][SxB[i]]);
    };
    // prologue: A(0),B(0) then A(1) -> 10 outstanding; vmcnt(4) retires ktile0
    stageA(0); stageB(0);
    if (nkt > 1) { stageA(1); asm volatile("s_waitcnt vmcnt(4)" ::: "memory"); }
    else         asm volatile("s_waitcnt vmcnt(0)" ::: "memory");
    BARRIER();

#pragma unroll 2
    for (int m = 0; m < nkt; m++) {
        int buf = m & 1;
        short8 af0[4], bf0[4], af1[4], bf1[4];
        // ---- p0: read kc0; stage B(m+1); MFMA kc0
#pragma unroll
        for (int mt = 0; mt < 4; mt++) {
            int row = wm + mt * 16 + l15;
            af0[mt] = *(short8*)&lA[buf][row * 64 + (quad ^ (row & 7)) * 8];
        }
#pragma unroll
        for (int nt = 0; nt < 4; nt++) {
            int row = wn + nt * 16 + l15;
            bf0[nt] = *(short8*)&lB[buf][row * 64 + (quad ^ (row & 7)) * 8];
        }
        if (m + 1 < nkt) stageB(m + 1);
        BARRIER();
        __builtin_amdgcn_s_setprio(1);
#pragma unroll
        for (int mt = 0; mt < 4; mt++)
#pragma unroll
            for (int nt = 0; nt < 4; nt++)
                acc[mt][nt] = __builtin_amdgcn_mfma_f32_16x16x32_bf16(
                    af0[mt], bf0[nt], acc[mt][nt], 0, 0, 0);
        __builtin_amdgcn_s_setprio(0);
        BARRIER();
        // ---- p1: read kc1; all-buf-reads-done barrier; stage A(m+2) into
        //          buf; MFMA kc1; counted wait for ktile m+1
#pragma unroll
        for (int mt = 0; mt < 4; mt++) {
            int row = wm + mt * 16 + l15;
            af1[mt] = *(short8*)&lA[buf][row * 64 + ((4 + quad) ^ (row & 7)) * 8];
        }
#pragma unroll
        for (int nt = 0; nt < 4; nt++) {
            int row = wn + nt * 16 + l15;
            bf1[nt] = *(short8*)&lB[buf][row * 64 + ((4 + quad) ^ (row & 7)) * 8];
        }
        asm volatile("s_waitcnt lgkmcnt(0)" ::: "memory");  // this wave's buf reads done
        BARRIER();                                          // all waves' done
        if (m + 2 < nkt) stageA(m + 2);   // into buf, now read-free
        __builtin_amdgcn_s_setprio(1);
#pragma unroll
        for (int mt = 0; mt < 4; mt++)
#pragma unroll
            for (int nt = 0; nt < 4; nt++)
                acc[mt][nt] = __builtin_amdgcn_mfma_f32_16x16x32_bf16(
                    af1[mt], bf1[nt], acc[mt][nt], 0, 0, 0);
        __builtin_amdgcn_s_setprio(0);
        if (m + 1 < nkt) {
            if (m + 2 < nkt) asm volatile("s_waitcnt vmcnt(4)" ::: "memory");
            else             asm volatile("s_waitcnt vmcnt(0)" ::: "memory");
        }
        BARRIER();
    }
#pragma unroll
    for (int mt = 0; mt < 4; mt++) {
#pragma unroll
        for (int nt = 0; nt < 4; nt++) {
            int col = bn * 128 + wn + nt * 16 + l15;
            float bv = bias ? bias[col] : 0.0f;
#pragma unroll
            for (int r = 0; r < 4; r++) {
                int row = bm * 256 + wm + mt * 16 + quad * 4 + r;
                float v = acc[mt][nt][r] + bv;
                if (RELU) v = fmaxf(v, 0.0f);
                if (res) v += res[(size_t)row * N + col];
                if (OUTF32)
                    ((float*)Cout)[(size_t)row * N + col] = v;
                else
                    ((short*)Cout)[(size_t)row * N + col] = f2b(v);
            }
        }
    }
}

// ---------------------------------------------------------------------------
// Flash attention v4.1: swapped-QK^T 32x32x16 MFMA, P fully in registers.
// 1D grid 1024, block 256 = 4 waves, 32 q/wave, KVBLK=64. See r3 notes.
// ---------------------------------------------------------------------------
__global__ __launch_bounds__(256, 4) void attn_kernel(const short* __restrict__ qkv,
                                                      const short* __restrict__ vt,
                                                      short* __restrict__ out) {
    __shared__ short lK[2][64 * 64];
    __shared__ short lV[2][64 * 64];
    __shared__ float lsbuf[4][32];
    int t = threadIdx.x;
    int w = t >> 6, lane = t & 63, l31 = lane & 31, hi = lane >> 5;
    int lin = blockIdx.x;
    int xcd = lin & 7, slot = lin >> 3;
    int hb = xcd * 8 + (slot & 7);   // 64 (b,h) combos, 8 per XCD
    int qt = slot >> 3;              // 0..15
    int b = hb >> 4, h = hb & 15;
    int qrow0 = b * 2048 + qt * 128 + w * 32;

    // Q B-fragments (col = q = l31, k = d = ks*16 + hi*8 + j),
    // prescaled by 2^-5 * log2(e)
    short8 qb[4];
#pragma unroll
    for (int ks = 0; ks < 4; ks++) {
        short8 q = *(const short8*)(qkv + (size_t)(qrow0 + l31) * 3072 +
                                    h * 64 + ks * 16 + hi * 8);
#pragma unroll
        for (int i = 0; i < 8; i++) q[i] = f2b(b2f(q[i]) * 0.04508422f);
        qb[ks] = q;
    }

    float l_s = 0.f;
    floatx16 o0 = {}, o1 = {};   // O cols d = l31 (+32 for o1), rows q = crow

    int S0 = t, S1 = 256 + t;
    int r0 = S0 >> 3, c0 = (S0 & 7) ^ (r0 & 7);
    int r1 = S1 >> 3, c1 = (S1 & 7) ^ (r1 & 7);
    const short* Kg0 = qkv + (size_t)(b * 2048 + r0) * 3072 + 1024 + h * 64 + c0 * 8;
    const short* Kg1 = qkv + (size_t)(b * 2048 + r1) * 3072 + 1024 + h * 64 + c1 * 8;
    const short* Vg0 = vt + (size_t)hb * 131072 + (size_t)r0 * 2048 + c0 * 8;
    const short* Vg1 = vt + (size_t)hb * 131072 + (size_t)r1 * 2048 + c1 * 8;

    auto stage = [&](int kt, int bufi) {
        int key0 = kt * 64;
        g2l16(Kg0 + (size_t)key0 * 3072, &lK[bufi][S0 * 8]);
        g2l16(Kg1 + (size_t)key0 * 3072, &lK[bufi][S1 * 8]);
        g2l16(Vg0 + key0, &lV[bufi][S0 * 8]);
        g2l16(Vg1 + key0, &lV[bufi][S1 * 8]);
    };

    stage(0, 0);
#pragma unroll 2
    for (int kt = 0; kt < 32; kt++) {
        int cur = kt & 1;
        __syncthreads();               // drains vmcnt: buf[cur] ready; WAR ok
        if (kt < 31) stage(kt + 1, cur ^ 1);   // lands during compute below

        // S^T = K (Q*2^-5*log2e)^T : s0 = keys 0..31, s1 = keys 32..63
        floatx16 s0 = {}, s1 = {};
#pragma unroll
        for (int ks = 0; ks < 4; ks++) {
            int cd = ks * 2 + hi;
            int ra = l31, rb = 32 + l31;
            short8 ka = *(short8*)&lK[cur][ra * 64 + ((cd ^ (ra & 7))) * 8];
            short8 kb = *(short8*)&lK[cur][rb * 64 + ((cd ^ (rb & 7))) * 8];
            s0 = __builtin_amdgcn_mfma_f32_32x32x16_bf16(ka, qb[ks], s0, 0, 0, 0);
            s1 = __builtin_amdgcn_mfma_f32_32x32x16_bf16(kb, qb[ks], s1, 0, 0, 0);
        }

        // p = 2^S in place; lane-local partial row-sum (this lane's 32 keys)
        float ps = 0.f;
#pragma unroll
        for (int r = 0; r < 16; r++) {
            float e0 = __builtin_amdgcn_exp2f(s0[r]);
            float e1 = __builtin_amdgcn_exp2f(s1[r]);
            s0[r] = e0; s1[r] = e1;
            ps += e0 + e1;
        }
        l_s += ps;

        // O += P V ; P frag = cvt_pk of adjacent regs (keys pre-matched by
        // the vt column permutation)
#pragma unroll
        for (int ks = 0; ks < 4; ks++) {
            unsigned w0, w1, w2, w3;
            if (ks == 0) {
                w0 = cvtpk(s0[0], s0[1]);  w1 = cvtpk(s0[2], s0[3]);
                w2 = cvtpk(s0[4], s0[5]);  w3 = cvtpk(s0[6], s0[7]);
            } else if (ks == 1) {
                w0 = cvtpk(s0[8], s0[9]);  w1 = cvtpk(s0[10], s0[11]);
                w2 = cvtpk(s0[12], s0[13]); w3 = cvtpk(s0[14], s0[15]);
            } else if (ks == 2) {
                w0 = cvtpk(s1[0], s1[1]);  w1 = cvtpk(s1[2], s1[3]);
                w2 = cvtpk(s1[4], s1[5]);  w3 = cvtpk(s1[6], s1[7]);
            } else {
                w0 = cvtpk(s1[8], s1[9]);  w1 = cvtpk(s1[10], s1[11]);
                w2 = cvtpk(s1[12], s1[13]); w3 = cvtpk(s1[14], s1[15]);
            }
            short8 pa = __builtin_bit_cast(short8, (uint4v){w0, w1, w2, w3});
            int cd = ks * 2 + hi;
            int ra = l31, rb = 32 + l31;
            short8 va = *(short8*)&lV[cur][ra * 64 + ((cd ^ (ra & 7))) * 8];
            short8 vb = *(short8*)&lV[cur][rb * 64 + ((cd ^ (rb & 7))) * 8];
            o0 = __builtin_amdgcn_mfma_f32_32x32x16_bf16(pa, va, o0, 0, 0, 0);
            o1 = __builtin_amdgcn_mfma_f32_32x32x16_bf16(pa, vb, o1, 0, 0, 0);
        }
    }

    // full row-sum: this lane's half + partner half (lane ^ 32, same q)
    float tot = l_s + __shfl_xor(l_s, 32);
    if (lane < 32) lsbuf[w][l31] = 1.0f / tot;
    __syncthreads();   // order ds_write before cross-lane ds_read

#pragma unroll
    for (int r = 0; r < 16; r++) {
        int qd = (r & 3) + 8 * (r >> 2) + 4 * hi;
        float rls = lsbuf[w][qd];
        size_t rowoff = (size_t)(qrow0 + qd) * 1024 + h * 64 + l31;
        out[rowoff] = f2b(o0[r] * rls);
        out[rowoff + 32] = f2b(o1[r] * rls);
    }
}

// ---------------------------------------------------------------------------
extern "C" void kernel_launch(void* const* d_in, const int* in_sizes, int n_in,
                              void* d_out, int out_size, void* d_ws, size_t ws_size,
                              hipStream_t stream) {
    const float* x      = (const float*)d_in[0];
    const float* w_qkv  = (const float*)d_in[1];
    const float* w_out  = (const float*)d_in[2];
    const float* b_out  = (const float*)d_in[3];
    const float* w1     = (const float*)d_in[4];
    const float* b1     = (const float*)d_in[5];
    const float* w2     = (const float*)d_in[6];
    const float* b2     = (const float*)d_in[7];
    const float* gamma1 = (const float*)d_in[8];
    const float* beta1  = (const float*)d_in[9];
    const float* gamma2 = (const float*)d_in[10];
    const float* beta2  = (const float*)d_in[11];
    float* out = (float*)d_out;

    // Workspace layout (byte offsets, 136MB high-water):
    //   0: wqkvT 6MB | 6: woutT 2MB | 8: w1T 8MB | 16: w2T 8MB
    //  24: h1 16MB (LN1 out -> attn out -> LN2 out)
    //  40: qkv 48MB + 88: vt 16MB  (both dead after attn; ff1 64MB spans both)
    // 104: x2 fp32 32MB (live to end)
    char* ws = (char*)d_ws;
    const size_t MB = 1024u * 1024u;
    short* wqkvT = (short*)(ws + 0 * MB);
    short* woutT = (short*)(ws + 6 * MB);
    short* w1T   = (short*)(ws + 8 * MB);
    short* w2T   = (short*)(ws + 16 * MB);
    short* h1    = (short*)(ws + 24 * MB);
    short* qkv   = (short*)(ws + 40 * MB);
    short* vt    = (short*)(ws + 88 * MB);
    short* ff1   = (short*)(ws + 40 * MB);
    float* x2    = (float*)(ws + 104 * MB);
    short* attn  = h1;   // h1 dead after QKV gemm
    short* h2    = h1;   // attn out dead after Wout gemm

    dim3 blk(256);
    transpose_w<<<dim3(96, 32), blk, 0, stream>>>(w_qkv, wqkvT, 1024, 3072);
    transpose_w<<<dim3(32, 32), blk, 0, stream>>>(w_out, woutT, 1024, 1024);
    transpose_w<<<dim3(128, 32), blk, 0, stream>>>(w1, w1T, 1024, 4096);
    transpose_w<<<dim3(32, 128), blk, 0, stream>>>(w2, w2T, 4096, 1024);

    ln_kernel<<<8192, blk, 0, stream>>>(x, gamma1, beta1, h1);
    gemm_bt_k64<0, 0><<<dim3(24, 64), blk, 0, stream>>>(h1, wqkvT, nullptr, nullptr,
                                                        qkv, 8192, 3072, 1024);
    vtprep_kernel<<<dim3(64, 2, 64), blk, 0, stream>>>(qkv, vt);
    attn_kernel<<<dim3(1024), blk, 0, stream>>>(qkv, vt, attn);
    // Wout + FF2 on the pipelined 256x128 kernel: 256 blocks = 1/CU
    gemm256n128<0, 1><<<dim3(256), dim3(512), 0, stream>>>(attn, woutT, b_out, x, x2,
                                                           8192, 1024, 1024);
    ln_kernel<<<8192, blk, 0, stream>>>(x2, gamma2, beta2, h2);
    // FF1 on the 256^2 8-phase kernel: 32x16 = 512 blocks = 2 clean rounds
    gemm256<1, 0><<<dim3(512), dim3(512), 0, stream>>>(h2, w1T, b1, nullptr, ff1,
                                                       8192, 4096, 1024);
    gemm256n128<0, 1><<<dim3(256), dim3(512), 0, stream>>>(ff1, w2T, b2, x2, out,
                                                           8192, 1024, 4096);
}

// Round 7
// 483.538 us; speedup vs baseline: 1.0788x; 1.0135x over previous
//
#include <hip/hip_runtime.h>
#include <hip/hip_bf16.h>
#include <stdint.h>

// Harness contract: reference is pure fp32 => all d_in are float*, d_out is
// float*. We convert to bf16 internally for MFMA, accumulate fp32.

typedef __attribute__((ext_vector_type(8))) short short8;   // 8 bf16 = 4 VGPRs (MFMA A/B frag)
typedef __attribute__((ext_vector_type(4))) short short4v;  // 4 bf16 = 8B
typedef __attribute__((ext_vector_type(4))) float floatx4;  // MFMA C/D frag (16x16)
typedef __attribute__((ext_vector_type(16))) float floatx16; // MFMA C/D frag (32x32)
typedef __attribute__((ext_vector_type(4))) unsigned uint4v;

#define DEV static __device__ __forceinline__

DEV float b2f(short s) {
    unsigned u = ((unsigned)(unsigned short)s) << 16;
    return __uint_as_float(u);
}
DEV short f2b(float f) {  // round-to-nearest-even bf16
    unsigned u = __float_as_uint(f);
    u += 0x7fffu + ((u >> 16) & 1u);
    return (short)(u >> 16);
}
DEV unsigned cvtpk(float a, float b) {  // pack {bf16(a) lo, bf16(b) hi}, RNE
    unsigned r;
    asm("v_cvt_pk_bf16_f32 %0, %1, %2" : "=v"(r) : "v"(a), "v"(b));
    return r;
}

// async global->LDS, 16B per lane; HW writes lane i at wavebase + i*16
// (pass per-lane LDS ptr = base + lane*16 so source layout matches HW).
typedef const __attribute__((address_space(1))) unsigned gu32;
typedef __attribute__((address_space(3))) unsigned lu32;
DEV void g2l16(const void* g, void* l) {
    __builtin_amdgcn_global_load_lds((gu32*)(uintptr_t)g,
                                     (lu32*)(unsigned)(uintptr_t)l, 16, 0, 0);
}

#define BARRIER() do { asm volatile("" ::: "memory"); \
    __builtin_amdgcn_s_barrier(); \
    asm volatile("" ::: "memory"); } while (0)

// ---------------------------------------------------------------------------
// LayerNorm: y = gamma*(x-mean)/(std+eps)+beta, std = sqrt(sum((x-m)^2)/(n-1))
// fp32 in, bf16 out. one row (1024) per block of 256 threads
// ---------------------------------------------------------------------------
__global__ __launch_bounds__(256) void ln_kernel(const float* __restrict__ x,
                                                 const float* __restrict__ gamma,
                                                 const float* __restrict__ beta,
                                                 short* __restrict__ y) {
    int row = blockIdx.x;
    int t = threadIdx.x;
    float4 v = *(const float4*)(x + (size_t)row * 1024 + t * 4);
    float f[4] = {v.x, v.y, v.z, v.w};
    float s = 0.f, ss = 0.f;
#pragma unroll
    for (int i = 0; i < 4; i++) { s += f[i]; ss += f[i] * f[i]; }
#pragma unroll
    for (int off = 32; off; off >>= 1) { s += __shfl_xor(s, off); ss += __shfl_xor(ss, off); }
    __shared__ float rs[4], rss[4];
    int wid = t >> 6, lane = t & 63;
    if (lane == 0) { rs[wid] = s; rss[wid] = ss; }
    __syncthreads();
    s = rs[0] + rs[1] + rs[2] + rs[3];
    ss = rss[0] + rss[1] + rss[2] + rss[3];
    float mean = s * (1.0f / 1024.0f);
    float var = (ss - 1024.0f * mean * mean) * (1.0f / 1023.0f);
    var = fmaxf(var, 0.0f);
    float inv = 1.0f / (sqrtf(var) + 1e-5f);
    float4 g = *(const float4*)(gamma + t * 4);
    float4 bb = *(const float4*)(beta + t * 4);
    short4v o;
    o[0] = f2b(g.x * (f[0] - mean) * inv + bb.x);
    o[1] = f2b(g.y * (f[1] - mean) * inv + bb.y);
    o[2] = f2b(g.z * (f[2] - mean) * inv + bb.z);
    o[3] = f2b(g.w * (f[3] - mean) * inv + bb.w);
    *(short4v*)(y + (size_t)row * 1024 + t * 4) = o;
}

// ---------------------------------------------------------------------------
// Weight transpose + fp32->bf16: out[c*R + r] = bf16(in[r*C + c])
// ---------------------------------------------------------------------------
__global__ __launch_bounds__(256) void transpose_w(const float* __restrict__ in,
                                                   short* __restrict__ out,
                                                   int R, int C) {
    __shared__ short tile[32][33];
    int tx = threadIdx.x & 31, ty = threadIdx.x >> 5;
    int c0 = blockIdx.x * 32, r0 = blockIdx.y * 32;
#pragma unroll
    for (int i = 0; i < 4; i++)
        tile[ty + i * 8][tx] = f2b(in[(size_t)(r0 + ty + i * 8) * C + c0 + tx]);
    __syncthreads();
#pragma unroll
    for (int i = 0; i < 4; i++)
        out[(size_t)(c0 + ty + i * 8) * R + r0 + tx] = tile[tx][ty + i * 8];
}

// ---------------------------------------------------------------------------
// V^T prep: vt[bh][d][kpos] = qkv[b*2048+key][2048 + h*64 + d]  (bf16->bf16)
// Key columns PRE-PERMUTED within each 16-key group so that the attention
// PV MFMA (32x32x16, A=P) B-operand k-slot (hi*8+j) maps to key
//   perm(s) = (s&3) + 8*((s>>2)&1) + 4*(s>>3)   (involution: swaps bits 2,3)
// which is exactly the key each lane holds in its swapped-QK^T C-regs
// (crow(r,hi) = (r&3)+8*(r>>2)+4*hi). P fragments become lane-local.
// grid: (64 key-tiles, 2 dim-tiles, 64 bh)
// ---------------------------------------------------------------------------
__global__ __launch_bounds__(256) void vtprep_kernel(const short* __restrict__ qkv,
                                                     short* __restrict__ vt) {
    __shared__ short tile[32][33];
    int tx = threadIdx.x & 31, ty = threadIdx.x >> 5;
    int bh = blockIdx.z, b = bh >> 4, h = bh & 15;
    int k0 = blockIdx.x * 32, d0 = blockIdx.y * 32;
#pragma unroll
    for (int i = 0; i < 4; i++)
        tile[ty + i * 8][tx] =
            qkv[(size_t)(b * 2048 + k0 + ty + i * 8) * 3072 + 2048 + h * 64 + d0 + tx];
    __syncthreads();
    // key (tx) -> column position (perm is its own inverse)
    int k15 = tx & 15;
    int kpos = (tx & 16) + ((k15 >> 2) & 1) * 8 + (k15 & 3) + ((k15 >> 3) & 1) * 4;
#pragma unroll
    for (int i = 0; i < 4; i++)
        vt[(size_t)bh * 131072 + (size_t)(d0 + ty + i * 8) * 2048 + k0 + kpos] =
            tile[tx][ty + i * 8];
}

// ---------------------------------------------------------------------------
// GEMM (BK=64, r3-proven): C = A * Bt^T (+bias)(relu)(+res). Tile 128x128,
// 4 waves, 32KB LDS -> 3 blocks/CU. Used for QKV. 0 bank conflicts.
// ---------------------------------------------------------------------------
template <int RELU, int OUTF32>
__global__ __launch_bounds__(256) void gemm_bt_k64(const short* __restrict__ A,
                                                   const short* __restrict__ Bt,
                                                   const float* __restrict__ bias,
                                                   const float* __restrict__ res,
                                                   void* __restrict__ Cout,
                                                   int M, int N, int K) {
    __shared__ short lA[128 * 64];
    __shared__ short lB[128 * 64];
    int t = threadIdx.x;
    int bn = blockIdx.x, bm = blockIdx.y;
    int w = t >> 6, lane = t & 63, quad = lane >> 4, l15 = lane & 15;
    int wm = (w >> 1) * 64, wn = (w & 1) * 64;
    floatx4 acc[4][4] = {};
    const int nkt = K >> 6;
    const short* Ag[4]; const short* Bg[4];
    short* lAp[4]; short* lBp[4];
#pragma unroll
    for (int i = 0; i < 4; i++) {
        int S = i * 256 + t;
        int r = S >> 3, c = (S & 7) ^ (r & 7);
        Ag[i] = A + (size_t)(bm * 128 + r) * K + c * 8;
        Bg[i] = Bt + (size_t)(bn * 128 + r) * K + c * 8;
        lAp[i] = &lA[S * 8];
        lBp[i] = &lB[S * 8];
    }
    for (int kt = 0; kt < nkt; kt++) {
#pragma unroll
        for (int i = 0; i < 4; i++) {
            g2l16(Ag[i] + kt * 64, lAp[i]);
            g2l16(Bg[i] + kt * 64, lBp[i]);
        }
        __syncthreads();   // drains vmcnt(0)
        short8 af[2][4], bf[2][4];
#pragma unroll
        for (int kc = 0; kc < 2; kc++) {
#pragma unroll
            for (int mt = 0; mt < 4; mt++) {
                int row = wm + mt * 16 + l15;
                int c = (kc * 4 + quad) ^ (row & 7);
                af[kc][mt] = *(short8*)&lA[row * 64 + c * 8];
            }
#pragma unroll
            for (int nt = 0; nt < 4; nt++) {
                int row = wn + nt * 16 + l15;
                int c = (kc * 4 + quad) ^ (row & 7);
                bf[kc][nt] = *(short8*)&lB[row * 64 + c * 8];
            }
        }
#pragma unroll
        for (int kc = 0; kc < 2; kc++)
#pragma unroll
            for (int mt = 0; mt < 4; mt++)
#pragma unroll
                for (int nt = 0; nt < 4; nt++)
                    acc[mt][nt] = __builtin_amdgcn_mfma_f32_16x16x32_bf16(
                        af[kc][mt], bf[kc][nt], acc[mt][nt], 0, 0, 0);
        __syncthreads();
    }
#pragma unroll
    for (int mt = 0; mt < 4; mt++) {
#pragma unroll
        for (int nt = 0; nt < 4; nt++) {
            int col = bn * 128 + wn + nt * 16 + l15;
            float bv = bias ? bias[col] : 0.0f;
#pragma unroll
            for (int r = 0; r < 4; r++) {
                int row = bm * 128 + wm + mt * 16 + quad * 4 + r;
                float v = acc[mt][nt][r] + bv;
                if (RELU) v = fmaxf(v, 0.0f);
                if (res) v += res[(size_t)row * N + col];
                if (OUTF32)
                    ((float*)Cout)[(size_t)row * N + col] = v;
                else
                    ((short*)Cout)[(size_t)row * N + col] = f2b(v);
            }
        }
    }
}

// ---------------------------------------------------------------------------
// GEMM 256x256 8-phase (m201-template port, r5-proven on FF1). BK=64, 512
// threads = 8 waves (2M x 4N), per-wave 128x64 out (acc[8][4]), LDS 128KB,
// 1 block/CU. See r4 notes for the 4-phase/ktile schedule + FIFO accounting.
// vmcnt NEVER 0 mid-loop (T3+T4); setprio = T5; XOR swizzle = T2 (0 confl).
// Grid 1D, XCD-chunked: xcd=lin&7 -> bm = xcd*4 + (s&3), bn = s>>2 (M=8192).
// ---------------------------------------------------------------------------
template <int RELU, int OUTF32>
__global__ __launch_bounds__(512, 2) void gemm256(const short* __restrict__ A,
                                                  const short* __restrict__ Bt,
                                                  const float* __restrict__ bias,
                                                  const float* __restrict__ res,
                                                  void* __restrict__ Cout,
                                                  int M, int N, int K) {
    __shared__ short lA[2][256 * 64];
    __shared__ short lB[2][256 * 64];
    int t = threadIdx.x;
    int lin = blockIdx.x;
    int xcd = lin & 7, s = lin >> 3;
    int bm = xcd * 4 + (s & 3);   // M=8192 -> 32 m-tiles, 4 per XCD chunk
    int bn = s >> 2;
    int w = t >> 6, lane = t & 63, quad = lane >> 4, l15 = lane & 15;
    int wm = (w >> 2) * 128, wn = (w & 3) * 64;
    floatx4 acc[8][4] = {};
    const int nkt = K >> 6;
    const short* Ag[4]; const short* Bg[4];
    int Sx[4];
#pragma unroll
    for (int i = 0; i < 4; i++) {
        int S = i * 512 + t;
        int r = S >> 3, c = (S & 7) ^ (r & 7);
        Ag[i] = A + (size_t)(bm * 256 + r) * K + c * 8;
        Bg[i] = Bt + (size_t)(bn * 256 + r) * K + c * 8;
        Sx[i] = S * 8;
    }
    // piece j of ktile kt: j<4 -> A round j; j>=4 -> B round j-4
    auto piece = [&](int kt, int j) {
        int buf = kt & 1;
        if (j < 4) g2l16(Ag[j] + kt * 64, &lA[buf][Sx[j]]);
        else       g2l16(Bg[j - 4] + kt * 64, &lB[buf][Sx[j - 4]]);
    };
    // prologue: ktile0 all 8 pieces, ktile1 A-part (matches steady-state FIFO)
#pragma unroll
    for (int j = 0; j < 8; j++) piece(0, j);
    if (nkt > 1) { piece(1, 0); piece(1, 1); piece(1, 2); piece(1, 3); }
    if (nkt > 1) asm volatile("s_waitcnt vmcnt(4)" ::: "memory");
    else         asm volatile("s_waitcnt vmcnt(0)" ::: "memory");
    BARRIER();

#pragma unroll 2
    for (int m = 0; m < nkt; m++) {
        int buf = m & 1;
        short8 af0[8], bf0[4], af1[8], bf1[4];
        // ---- p0: read kc0; stage B01(m+1); MFMA mt0-3 kc0
#pragma unroll
        for (int mt = 0; mt < 8; mt++) {
            int row = wm + mt * 16 + l15;
            af0[mt] = *(short8*)&lA[buf][row * 64 + (quad ^ (row & 7)) * 8];
        }
#pragma unroll
        for (int nt = 0; nt < 4; nt++) {
            int row = wn + nt * 16 + l15;
            bf0[nt] = *(short8*)&lB[buf][row * 64 + (quad ^ (row & 7)) * 8];
        }
        if (m + 1 < nkt) { piece(m + 1, 4); piece(m + 1, 5); }
        BARRIER();
        __builtin_amdgcn_s_setprio(1);
#pragma unroll
        for (int mt = 0; mt < 4; mt++)
#pragma unroll
            for (int nt = 0; nt < 4; nt++)
                acc[mt][nt] = __builtin_amdgcn_mfma_f32_16x16x32_bf16(
                    af0[mt], bf0[nt], acc[mt][nt], 0, 0, 0);
        __builtin_amdgcn_s_setprio(0);
        BARRIER();
        // ---- p1: read kc1; stage B23(m+1); MFMA mt4-7 kc0
#pragma unroll
        for (int mt = 0; mt < 8; mt++) {
            int row = wm + mt * 16 + l15;
            af1[mt] = *(short8*)&lA[buf][row * 64 + ((4 + quad) ^ (row & 7)) * 8];
        }
#pragma unroll
        for (int nt = 0; nt < 4; nt++) {
            int row = wn + nt * 16 + l15;
            bf1[nt] = *(short8*)&lB[buf][row * 64 + ((4 + quad) ^ (row & 7)) * 8];
        }
        if (m + 1 < nkt) { piece(m + 1, 6); piece(m + 1, 7); }
        BARRIER();
        __builtin_amdgcn_s_setprio(1);
#pragma unroll
        for (int mt = 4; mt < 8; mt++)
#pragma unroll
            for (int nt = 0; nt < 4; nt++)
                acc[mt][nt] = __builtin_amdgcn_mfma_f32_16x16x32_bf16(
                    af0[mt], bf0[nt], acc[mt][nt], 0, 0, 0);
        __builtin_amdgcn_s_setprio(0);
        asm volatile("s_waitcnt lgkmcnt(0)" ::: "memory");  // all buf reads done
        BARRIER();
        // ---- p2: stage A01(m+2) into buf (read-free now); MFMA mt0-3 kc1
        if (m + 2 < nkt) { piece(m + 2, 0); piece(m + 2, 1); }
        BARRIER();
        __builtin_amdgcn_s_setprio(1);
#pragma unroll
        for (int mt = 0; mt < 4; mt++)
#pragma unroll
            for (int nt = 0; nt < 4; nt++)
                acc[mt][nt] = __builtin_amdgcn_mfma_f32_16x16x32_bf16(
                    af1[mt], bf1[nt], acc[mt][nt], 0, 0, 0);
        __builtin_amdgcn_s_setprio(0);
        BARRIER();
        // ---- p3: stage A23(m+2); MFMA mt4-7 kc1; counted wait for m+1
        if (m + 2 < nkt) { piece(m + 2, 2); piece(m + 2, 3); }
        BARRIER();
        __builtin_amdgcn_s_setprio(1);
#pragma unroll
        for (int mt = 4; mt < 8; mt++)
#pragma unroll
            for (int nt = 0; nt < 4; nt++)
                acc[mt][nt] = __builtin_amdgcn_mfma_f32_16x16x32_bf16(
                    af1[mt], bf1[nt], acc[mt][nt], 0, 0, 0);
        __builtin_amdgcn_s_setprio(0);
        if (m + 1 < nkt) {
            if (m + 2 < nkt) asm volatile("s_waitcnt vmcnt(4)" ::: "memory");
            else             asm volatile("s_waitcnt vmcnt(0)" ::: "memory");
        }
        BARRIER();
    }
#pragma unroll
    for (int mt = 0; mt < 8; mt++) {
#pragma unroll
        for (int nt = 0; nt < 4; nt++) {
            int col = bn * 256 + wn + nt * 16 + l15;
            float bv = bias ? bias[col] : 0.0f;
#pragma unroll
            for (int r = 0; r < 4; r++) {
                int row = bm * 256 + wm + mt * 16 + quad * 4 + r;
                float v = acc[mt][nt][r] + bv;
                if (RELU) v = fmaxf(v, 0.0f);
                if (res) v += res[(size_t)row * N + col];
                if (OUTF32)
                    ((float*)Cout)[(size_t)row * N + col] = v;
                else
                    ((short*)Cout)[(size_t)row * N + col] = f2b(v);
            }
        }
    }
}

// ---------------------------------------------------------------------------
// GEMM 256x128 pipelined v2 (for the N=1024 GEMMs: Wout, FF2). BK=64, 512
// threads = 8 waves (4M x 2N), per-wave 64x64 (acc[4][4]), LDS 96KB, 1
// block/CU, grid 256 = 1/CU, XCD-chunked.
// r6 regression fix: FRONT-LOAD all 16 ds_reads into p0 (r6's read-every-
// phase form left no read-free phases for the LDS queue to drain: FF2 97µs,
// MfmaUtil 28% < k128's 33%). Now, like gemm256, half the ktile is pure
// MFMA, and barriers drop 4->3/ktile, lgkm drains 2->1:
//   p0: 16 ds_reads (af0,bf0,af1,bf1); stage B(m+1) [other buf]; BARRIER;
//       MFMA kc0 (setprio); lgkmcnt(0) [cheap: reads issued pre-barrier,
//       covered by barrier + 16 MFMA]; BARRIER  -> buf globally read-free
//   p1: stage A(m+2) into buf; MFMA kc1 (setprio); counted vmcnt; BARRIER
// FIFO (6 pieces/ktile/thread): A(j)@(j-2).p1, B(j)@(j-1).p0. At p1-end:
// outstanding = A(m+1)4+B(m+1)2+A(m+2)4 = 10 -> vmcnt(4) retires exactly
// ktile m+1. vmcnt NEVER 0 mid-loop (T3+T4); setprio T5; XOR swizzle T2.
// Races: B(m+1) overwrites lB[buf^1] (readers done at (m-1).p0 lgkm+bar);
// A(m+2) overwrites lA[buf] (readers done at m.p0 lgkm+bar). Tail as before.
// ---------------------------------------------------------------------------
template <int RELU, int OUTF32>
__global__ __launch_bounds__(512, 2) void gemm256n128(const short* __restrict__ A,
                                                      const short* __restrict__ Bt,
                                                      const float* __restrict__ bias,
                                                      const float* __restrict__ res,
                                                      void* __restrict__ Cout,
                                                      int M, int N, int K) {
    __shared__ short lA[2][256 * 64];
    __shared__ short lB[2][128 * 64];
    int t = threadIdx.x;
    int lin = blockIdx.x;
    int xcd = lin & 7, s = lin >> 3;
    int bm = xcd * 4 + (s & 3);   // M=8192 -> 32 m-tiles, 4 per XCD chunk
    int bn = s >> 2;              // 0..7 (N=1024)
    int w = t >> 6, lane = t & 63, quad = lane >> 4, l15 = lane & 15;
    int wm = (w >> 1) * 64, wn = (w & 1) * 64;
    floatx4 acc[4][4] = {};
    const int nkt = K >> 6;
    const short* Ag[4]; const short* Bg[2];
    int SxA[4], SxB[2];
#pragma unroll
    for (int i = 0; i < 4; i++) {
        int S = i * 512 + t;
        int r = S >> 3, c = (S & 7) ^ (r & 7);
        Ag[i] = A + (size_t)(bm * 256 + r) * K + c * 8;
        SxA[i] = S * 8;
    }
#pragma unroll
    for (int i = 0; i < 2; i++) {
        int S = i * 512 + t;
        int r = S >> 3, c = (S & 7) ^ (r & 7);
        Bg[i] = Bt + (size_t)(bn * 128 + r) * K + c * 8;
        SxB[i] = S * 8;
    }
    auto stageA = [&](int kt) {
        int buf = kt & 1;
#pragma unroll
        for (int i = 0; i < 4; i++) g2l16(Ag[i] + kt * 64, &lA[buf][SxA[i]]);
    };
    auto stageB = [&](int kt) {
        int buf = kt & 1;
#pragma unroll
        for (int i = 0; i < 2; i++) g2l16(Bg[i] + kt * 64, &lB[buf][SxB[i]]);
    };
    // prologue: A(0),B(0) then A(1) -> 10 outstanding; vmcnt(4) retires ktile0
    stageA(0); stageB(0);
    if (nkt > 1) { stageA(1); asm volatile("s_waitcnt vmcnt(4)" ::: "memory"); }
    else         asm volatile("s_waitcnt vmcnt(0)" ::: "memory");
    BARRIER();

#pragma unroll 2
    for (int m = 0; m < nkt; m++) {
        int buf = m & 1;
        short8 af0[4], bf0[4], af1[4], bf1[4];
        // ---- p0: ALL 16 ds_reads; stage B(m+1); MFMA kc0; lgkm0
#pragma unroll
        for (int mt = 0; mt < 4; mt++) {
            int row = wm + mt * 16 + l15;
            af0[mt] = *(short8*)&lA[buf][row * 64 + (quad ^ (row & 7)) * 8];
        }
#pragma unroll
        for (int nt = 0; nt < 4; nt++) {
            int row = wn + nt * 16 + l15;
            bf0[nt] = *(short8*)&lB[buf][row * 64 + (quad ^ (row & 7)) * 8];
        }
#pragma unroll
        for (int mt = 0; mt < 4; mt++) {
            int row = wm + mt * 16 + l15;
            af1[mt] = *(short8*)&lA[buf][row * 64 + ((4 + quad) ^ (row & 7)) * 8];
        }
#pragma unroll
        for (int nt = 0; nt < 4; nt++) {
            int row = wn + nt * 16 + l15;
            bf1[nt] = *(short8*)&lB[buf][row * 64 + ((4 + quad) ^ (row & 7)) * 8];
        }
        if (m + 1 < nkt) stageB(m + 1);
        BARRIER();
        __builtin_amdgcn_s_setprio(1);
#pragma unroll
        for (int mt = 0; mt < 4; mt++)
#pragma unroll
            for (int nt = 0; nt < 4; nt++)
                acc[mt][nt] = __builtin_amdgcn_mfma_f32_16x16x32_bf16(
                    af0[mt], bf0[nt], acc[mt][nt], 0, 0, 0);
        __builtin_amdgcn_s_setprio(0);
        asm volatile("s_waitcnt lgkmcnt(0)" ::: "memory");  // af1/bf1 landed too
        BARRIER();                                          // buf read-free
        // ---- p1: stage A(m+2) into buf; MFMA kc1; counted wait for m+1
        if (m + 2 < nkt) stageA(m + 2);
        __builtin_amdgcn_s_setprio(1);
#pragma unroll
        for (int mt = 0; mt < 4; mt++)
#pragma unroll
            for (int nt = 0; nt < 4; nt++)
                acc[mt][nt] = __builtin_amdgcn_mfma_f32_16x16x32_bf16(
                    af1[mt], bf1[nt], acc[mt][nt], 0, 0, 0);
        __builtin_amdgcn_s_setprio(0);
        if (m + 1 < nkt) {
            if (m + 2 < nkt) asm volatile("s_waitcnt vmcnt(4)" ::: "memory");
            else             asm volatile("s_waitcnt vmcnt(0)" ::: "memory");
        }
        BARRIER();
    }
#pragma unroll
    for (int mt = 0; mt < 4; mt++) {
#pragma unroll
        for (int nt = 0; nt < 4; nt++) {
            int col = bn * 128 + wn + nt * 16 + l15;
            float bv = bias ? bias[col] : 0.0f;
#pragma unroll
            for (int r = 0; r < 4; r++) {
                int row = bm * 256 + wm + mt * 16 + quad * 4 + r;
                float v = acc[mt][nt][r] + bv;
                if (RELU) v = fmaxf(v, 0.0f);
                if (res) v += res[(size_t)row * N + col];
                if (OUTF32)
                    ((float*)Cout)[(size_t)row * N + col] = v;
                else
                    ((short*)Cout)[(size_t)row * N + col] = f2b(v);
            }
        }
    }
}

// ---------------------------------------------------------------------------
// Flash attention v4.1: swapped-QK^T 32x32x16 MFMA, P fully in registers.
// 1D grid 1024, block 256 = 4 waves, 32 q/wave, KVBLK=64. See r3 notes.
// ---------------------------------------------------------------------------
__global__ __launch_bounds__(256, 4) void attn_kernel(const short* __restrict__ qkv,
                                                      const short* __restrict__ vt,
                                                      short* __restrict__ out) {
    __shared__ short lK[2][64 * 64];
    __shared__ short lV[2][64 * 64];
    __shared__ float lsbuf[4][32];
    int t = threadIdx.x;
    int w = t >> 6, lane = t & 63, l31 = lane & 31, hi = lane >> 5;
    int lin = blockIdx.x;
    int xcd = lin & 7, slot = lin >> 3;
    int hb = xcd * 8 + (slot & 7);   // 64 (b,h) combos, 8 per XCD
    int qt = slot >> 3;              // 0..15
    int b = hb >> 4, h = hb & 15;
    int qrow0 = b * 2048 + qt * 128 + w * 32;

    // Q B-fragments (col = q = l31, k = d = ks*16 + hi*8 + j),
    // prescaled by 2^-5 * log2(e)
    short8 qb[4];
#pragma unroll
    for (int ks = 0; ks < 4; ks++) {
        short8 q = *(const short8*)(qkv + (size_t)(qrow0 + l31) * 3072 +
                                    h * 64 + ks * 16 + hi * 8);
#pragma unroll
        for (int i = 0; i < 8; i++) q[i] = f2b(b2f(q[i]) * 0.04508422f);
        qb[ks] = q;
    }

    float l_s = 0.f;
    floatx16 o0 = {}, o1 = {};   // O cols d = l31 (+32 for o1), rows q = crow

    int S0 = t, S1 = 256 + t;
    int r0 = S0 >> 3, c0 = (S0 & 7) ^ (r0 & 7);
    int r1 = S1 >> 3, c1 = (S1 & 7) ^ (r1 & 7);
    const short* Kg0 = qkv + (size_t)(b * 2048 + r0) * 3072 + 1024 + h * 64 + c0 * 8;
    const short* Kg1 = qkv + (size_t)(b * 2048 + r1) * 3072 + 1024 + h * 64 + c1 * 8;
    const short* Vg0 = vt + (size_t)hb * 131072 + (size_t)r0 * 2048 + c0 * 8;
    const short* Vg1 = vt + (size_t)hb * 131072 + (size_t)r1 * 2048 + c1 * 8;

    auto stage = [&](int kt, int bufi) {
        int key0 = kt * 64;
        g2l16(Kg0 + (size_t)key0 * 3072, &lK[bufi][S0 * 8]);
        g2l16(Kg1 + (size_t)key0 * 3072, &lK[bufi][S1 * 8]);
        g2l16(Vg0 + key0, &lV[bufi][S0 * 8]);
        g2l16(Vg1 + key0, &lV[bufi][S1 * 8]);
    };

    stage(0, 0);
#pragma unroll 2
    for (int kt = 0; kt < 32; kt++) {
        int cur = kt & 1;
        __syncthreads();               // drains vmcnt: buf[cur] ready; WAR ok
        if (kt < 31) stage(kt + 1, cur ^ 1);   // lands during compute below

        // S^T = K (Q*2^-5*log2e)^T : s0 = keys 0..31, s1 = keys 32..63
        floatx16 s0 = {}, s1 = {};
#pragma unroll
        for (int ks = 0; ks < 4; ks++) {
            int cd = ks * 2 + hi;
            int ra = l31, rb = 32 + l31;
            short8 ka = *(short8*)&lK[cur][ra * 64 + ((cd ^ (ra & 7))) * 8];
            short8 kb = *(short8*)&lK[cur][rb * 64 + ((cd ^ (rb & 7))) * 8];
            s0 = __builtin_amdgcn_mfma_f32_32x32x16_bf16(ka, qb[ks], s0, 0, 0, 0);
            s1 = __builtin_amdgcn_mfma_f32_32x32x16_bf16(kb, qb[ks], s1, 0, 0, 0);
        }

        // p = 2^S in place; lane-local partial row-sum (this lane's 32 keys)
        float ps = 0.f;
#pragma unroll
        for (int r = 0; r < 16; r++) {
            float e0 = __builtin_amdgcn_exp2f(s0[r]);
            float e1 = __builtin_amdgcn_exp2f(s1[r]);
            s0[r] = e0; s1[r] = e1;
            ps += e0 + e1;
        }
        l_s += ps;

        // O += P V ; P frag = cvt_pk of adjacent regs (keys pre-matched by
        // the vt column permutation)
#pragma unroll
        for (int ks = 0; ks < 4; ks++) {
            unsigned w0, w1, w2, w3;
            if (ks == 0) {
                w0 = cvtpk(s0[0], s0[1]);  w1 = cvtpk(s0[2], s0[3]);
                w2 = cvtpk(s0[4], s0[5]);  w3 = cvtpk(s0[6], s0[7]);
            } else if (ks == 1) {
                w0 = cvtpk(s0[8], s0[9]);  w1 = cvtpk(s0[10], s0[11]);
                w2 = cvtpk(s0[12], s0[13]); w3 = cvtpk(s0[14], s0[15]);
            } else if (ks == 2) {
                w0 = cvtpk(s1[0], s1[1]);  w1 = cvtpk(s1[2], s1[3]);
                w2 = cvtpk(s1[4], s1[5]);  w3 = cvtpk(s1[6], s1[7]);
            } else {
                w0 = cvtpk(s1[8], s1[9]);  w1 = cvtpk(s1[10], s1[11]);
                w2 = cvtpk(s1[12], s1[13]); w3 = cvtpk(s1[14], s1[15]);
            }
            short8 pa = __builtin_bit_cast(short8, (uint4v){w0, w1, w2, w3});
            int cd = ks * 2 + hi;
            int ra = l31, rb = 32 + l31;
            short8 va = *(short8*)&lV[cur][ra * 64 + ((cd ^ (ra & 7))) * 8];
            short8 vb = *(short8*)&lV[cur][rb * 64 + ((cd ^ (rb & 7))) * 8];
            o0 = __builtin_amdgcn_mfma_f32_32x32x16_bf16(pa, va, o0, 0, 0, 0);
            o1 = __builtin_amdgcn_mfma_f32_32x32x16_bf16(pa, vb, o1, 0, 0, 0);
        }
    }

    // full row-sum: this lane's half + partner half (lane ^ 32, same q)
    float tot = l_s + __shfl_xor(l_s, 32);
    if (lane < 32) lsbuf[w][l31] = 1.0f / tot;
    __syncthreads();   // order ds_write before cross-lane ds_read

#pragma unroll
    for (int r = 0; r < 16; r++) {
        int qd = (r & 3) + 8 * (r >> 2) + 4 * hi;
        float rls = lsbuf[w][qd];
        size_t rowoff = (size_t)(qrow0 + qd) * 1024 + h * 64 + l31;
        out[rowoff] = f2b(o0[r] * rls);
        out[rowoff + 32] = f2b(o1[r] * rls);
    }
}

// ---------------------------------------------------------------------------
extern "C" void kernel_launch(void* const* d_in, const int* in_sizes, int n_in,
                              void* d_out, int out_size, void* d_ws, size_t ws_size,
                              hipStream_t stream) {
    const float* x      = (const float*)d_in[0];
    const float* w_qkv  = (const float*)d_in[1];
    const float* w_out  = (const float*)d_in[2];
    const float* b_out  = (const float*)d_in[3];
    const float* w1     = (const float*)d_in[4];
    const float* b1     = (const float*)d_in[5];
    const float* w2     = (const float*)d_in[6];
    const float* b2     = (const float*)d_in[7];
    const float* gamma1 = (const float*)d_in[8];
    const float* beta1  = (const float*)d_in[9];
    const float* gamma2 = (const float*)d_in[10];
    const float* beta2  = (const float*)d_in[11];
    float* out = (float*)d_out;

    // Workspace layout (byte offsets, 136MB high-water):
    //   0: wqkvT 6MB | 6: woutT 2MB | 8: w1T 8MB | 16: w2T 8MB
    //  24: h1 16MB (LN1 out -> attn out -> LN2 out)
    //  40: qkv 48MB + 88: vt 16MB  (both dead after attn; ff1 64MB spans both)
    // 104: x2 fp32 32MB (live to end)
    char* ws = (char*)d_ws;
    const size_t MB = 1024u * 1024u;
    short* wqkvT = (short*)(ws + 0 * MB);
    short* woutT = (short*)(ws + 6 * MB);
    short* w1T   = (short*)(ws + 8 * MB);
    short* w2T   = (short*)(ws + 16 * MB);
    short* h1    = (short*)(ws + 24 * MB);
    short* qkv   = (short*)(ws + 40 * MB);
    short* vt    = (short*)(ws + 88 * MB);
    short* ff1   = (short*)(ws + 40 * MB);
    float* x2    = (float*)(ws + 104 * MB);
    short* attn  = h1;   // h1 dead after QKV gemm
    short* h2    = h1;   // attn out dead after Wout gemm

    dim3 blk(256);
    transpose_w<<<dim3(96, 32), blk, 0, stream>>>(w_qkv, wqkvT, 1024, 3072);
    transpose_w<<<dim3(32, 32), blk, 0, stream>>>(w_out, woutT, 1024, 1024);
    transpose_w<<<dim3(128, 32), blk, 0, stream>>>(w1, w1T, 1024, 4096);
    transpose_w<<<dim3(32, 128), blk, 0, stream>>>(w2, w2T, 4096, 1024);

    ln_kernel<<<8192, blk, 0, stream>>>(x, gamma1, beta1, h1);
    gemm_bt_k64<0, 0><<<dim3(24, 64), blk, 0, stream>>>(h1, wqkvT, nullptr, nullptr,
                                                        qkv, 8192, 3072, 1024);
    vtprep_kernel<<<dim3(64, 2, 64), blk, 0, stream>>>(qkv, vt);
    attn_kernel<<<dim3(1024), blk, 0, stream>>>(qkv, vt, attn);
    // Wout + FF2 on the pipelined 256x128 kernel: 256 blocks = 1/CU
    gemm256n128<0, 1><<<dim3(256), dim3(512), 0, stream>>>(attn, woutT, b_out, x, x2,
                                                           8192, 1024, 1024);
    ln_kernel<<<8192, blk, 0, stream>>>(x2, gamma2, beta2, h2);
    // FF1 on the 256^2 8-phase kernel: 32x16 = 512 blocks = 2 clean rounds
    gemm256<1, 0><<<dim3(512), dim3(512), 0, stream>>>(h2, w1T, b1, nullptr, ff1,
                                                       8192, 4096, 1024);
    gemm256n128<0, 1><<<dim3(256), dim3(512), 0, stream>>>(ff1, w2T, b2, x2, out,
                                                           8192, 1024, 4096);
}